// Round 4
// baseline (5406.221 us; speedup 1.0000x reference)
//
#include <hip/hip_runtime.h>
#include <hip/hip_bf16.h>
#include <cstdint>

// Model constants
#define B_SZ 128
#define L_SZ 150
#define E_SZ 150
#define HIDN 128
#define M_TOK (B_SZ*L_SZ)   // 19200
#define G3 384              // 3*HID gates
#define NFC 2304            // capsule-FC input count
#define NCH 72              // n-chunks per b (32 n each)

typedef __attribute__((ext_vector_type(8))) short bf16x8;
typedef __attribute__((ext_vector_type(4))) float f32x4;

__device__ __forceinline__ float sigm(float x){ return 1.f/(1.f+__expf(-x)); }

__device__ __forceinline__ void storeval(float* p, float v){ *p = v; }
__device__ __forceinline__ void storeval(__hip_bfloat16* p, float v){ *p = __float2bfloat16(v); }

// ---------------- kernel 1: c[t][32] = softmax over last-4 of code[x[t]] ----------------
__global__ void softmax_c_kernel(const float* __restrict__ code, const int* __restrict__ x,
                                 float* __restrict__ c){
  int idx = blockIdx.x*blockDim.x + threadIdx.x;
  if (idx >= M_TOK*8) return;
  int t = idx >> 3, j = idx & 7;
  int tok = x[t];
  const float* p = code + ((size_t)tok*32 + j*4);
  float a0=p[0],a1=p[1],a2=p[2],a3=p[3];
  float mx = fmaxf(fmaxf(a0,a1),fmaxf(a2,a3));
  float e0=__expf(a0-mx),e1=__expf(a1-mx),e2=__expf(a2-mx),e3=__expf(a3-mx);
  float inv = 1.f/(e0+e1+e2+e3);
  float* q = c + ((size_t)t*32 + j*4);
  q[0]=e0*inv; q[1]=e1*inv; q[2]=e2*inv; q[3]=e3*inv;
}

// ---------------- kernel 2: emb bf16 padded ----------------
__global__ void embed_bf16_kernel(const float* __restrict__ c, const float* __restrict__ cb,
                                  __hip_bfloat16* __restrict__ A0, int Kp){
  int idx = blockIdx.x*blockDim.x + threadIdx.x;
  if (idx >= M_TOK*160) return;
  int t = idx / 160; int e = idx - t*160;
  float acc = 0.f;
  if (e < E_SZ){
    const float* cr = c + (size_t)t*32;
    #pragma unroll
    for (int i=0;i<32;i++) acc += cr[i]*cb[i*E_SZ + e];
  }
  A0[(size_t)t*Kp + e] = __float2bfloat16(acc);
}

// ---------------- weight fp32->bf16 (K-padded) ----------------
__global__ void convW_kernel(const float* __restrict__ src, __hip_bfloat16* __restrict__ dst,
                             int N, int K, int Kp){
  int idx = blockIdx.x*blockDim.x + threadIdx.x;
  if (idx >= N*Kp) return;
  int n = idx / Kp; int k = idx - n*Kp;
  float v = (k < K) ? src[(size_t)n*K + k] : 0.f;
  dst[idx] = __float2bfloat16(v);
}

// ---------------- kernel 3: MFMA GEMM ----------------
__global__ __launch_bounds__(256) void gemm_mfma_kernel(
    const __hip_bfloat16* __restrict__ A, const __hip_bfloat16* __restrict__ W,
    const float* __restrict__ bias, float* __restrict__ out, int Kp)
{
  __shared__ __hip_bfloat16 As[128*32];
  __shared__ __hip_bfloat16 Bs[128*32];
  int tid = threadIdx.x;
  int m0 = blockIdx.y*128, n0 = blockIdx.x*128;
  int lane = tid & 63, wid = tid >> 6;
  int wr = wid >> 1, wc = wid & 1;
  int srow = tid >> 2, scol = (tid & 3) * 8;

  f32x4 acc[4][4];
  #pragma unroll
  for (int i=0;i<4;i++)
    #pragma unroll
    for (int j=0;j<4;j++) acc[i][j] = (f32x4){0.f,0.f,0.f,0.f};

  int r = lane & 15, kq = (lane >> 4) * 8;

  for (int k0 = 0; k0 < Kp; k0 += 32){
    __builtin_amdgcn_global_load_lds(
      (const __attribute__((address_space(1))) void*)(A + (size_t)(m0+srow)*Kp + k0 + scol),
      (__attribute__((address_space(3))) void*)(As + tid*8), 16, 0, 0);
    __builtin_amdgcn_global_load_lds(
      (const __attribute__((address_space(1))) void*)(A + (size_t)(m0+64+srow)*Kp + k0 + scol),
      (__attribute__((address_space(3))) void*)(As + 2048 + tid*8), 16, 0, 0);
    __builtin_amdgcn_global_load_lds(
      (const __attribute__((address_space(1))) void*)(W + (size_t)(n0+srow)*Kp + k0 + scol),
      (__attribute__((address_space(3))) void*)(Bs + tid*8), 16, 0, 0);
    __builtin_amdgcn_global_load_lds(
      (const __attribute__((address_space(1))) void*)(W + (size_t)(n0+64+srow)*Kp + k0 + scol),
      (__attribute__((address_space(3))) void*)(Bs + 2048 + tid*8), 16, 0, 0);
    __syncthreads();

    bf16x8 aF[4], bF[4];
    #pragma unroll
    for (int mi=0;mi<4;mi++) aF[mi] = *(const bf16x8*)(As + (wr*64 + mi*16 + r)*32 + kq);
    #pragma unroll
    for (int nj=0;nj<4;nj++) bF[nj] = *(const bf16x8*)(Bs + (wc*64 + nj*16 + r)*32 + kq);
    #pragma unroll
    for (int mi=0;mi<4;mi++)
      #pragma unroll
      for (int nj=0;nj<4;nj++)
        acc[mi][nj] = __builtin_amdgcn_mfma_f32_16x16x32_bf16(aF[mi], bF[nj], acc[mi][nj], 0, 0, 0);
    __syncthreads();
  }

  #pragma unroll
  for (int nj=0;nj<4;nj++){
    int n = n0 + wc*64 + nj*16 + (lane & 15);
    int dir = (n >= G3) ? 1 : 0; int g = n - dir*G3;
    float bv = bias[n];
    #pragma unroll
    for (int mi=0;mi<4;mi++){
      #pragma unroll
      for (int r2=0;r2<4;r2++){
        int m = m0 + wr*64 + mi*16 + (lane>>4)*4 + r2;
        out[((size_t)dir*M_TOK + m)*G3 + g] = acc[mi][nj][r2] + bv;
      }
    }
  }
}

// ---------------- kernel 4: GRU scan v2: 768 threads, K-split 2, gi prefetch ----------------
template <typename OT>
__global__ __launch_bounds__(768) void gru_scan_kernel(
    const float* __restrict__ gi, const float* __restrict__ whh,
    const float* __restrict__ bhh, OT* __restrict__ out, int rowStride, size_t dirOffset)
{
  int bx = blockIdx.x; int dir = bx>>7; int b = bx&127;
  int tid = threadIdx.x;
  int half = (tid >= 384) ? 1 : 0;
  int row = tid - half*384;
  __shared__ float s_h[128];
  __shared__ float s_part[2][384];
  float4 w[16];
  const float4* wrow = (const float4*)(whh + (size_t)(dir*G3 + row)*HIDN + half*64);
  #pragma unroll
  for (int i=0;i<16;i++) w[i] = wrow[i];
  float bias = (half==0) ? bhh[dir*G3 + row] : 0.f;
  if (tid < 128) s_h[tid] = 0.f;
  const float* gib = gi + ((size_t)dir*M_TOK + (size_t)b*L_SZ)*G3;
  float ir=0.f, iz=0.f, inn=0.f;
  {
    int t0 = dir ? (L_SZ-1) : 0;
    if (tid < 128){
      const float* gr = gib + (size_t)t0*G3;
      ir = gr[tid]; iz = gr[128+tid]; inn = gr[256+tid];
    }
  }
  __syncthreads();
  for (int s=0; s<L_SZ; ++s){
    int t = dir ? (L_SZ-1 - s) : s;
    const float4* h4 = ((const float4*)s_h) + half*16;
    float p0=bias, p1=0.f;
    #pragma unroll
    for (int i=0;i<16;i+=2){
      float4 ha=h4[i], hb=h4[i+1];
      p0 += w[i].x*ha.x + w[i].y*ha.y + w[i].z*ha.z + w[i].w*ha.w;
      p1 += w[i+1].x*hb.x + w[i+1].y*hb.y + w[i+1].z*hb.z + w[i+1].w*hb.w;
    }
    s_part[half][row] = p0+p1;
    // prefetch next-step gi (latency hidden under barrier + gates + next matvec)
    float nir=0.f, niz=0.f, ninn=0.f;
    if (tid < 128 && s+1 < L_SZ){
      int tn = dir ? (t-1) : (t+1);
      const float* gr = gib + (size_t)tn*G3;
      nir = gr[tid]; niz = gr[128+tid]; ninn = gr[256+tid];
    }
    __syncthreads();
    if (tid < 128){
      float hr = s_part[0][tid]     + s_part[1][tid];
      float hz = s_part[0][128+tid] + s_part[1][128+tid];
      float hn = s_part[0][256+tid] + s_part[1][256+tid];
      float rr = sigm(ir+hr);
      float zz = sigm(iz+hz);
      float xn = inn + rr*hn;
      float e2 = __expf(2.f*xn);
      float nn = 1.f - 2.f/(e2+1.f);
      float hnew = (1.f-zz)*nn + zz*s_h[tid];
      s_h[tid] = hnew;
      storeval(&out[(size_t)(b*L_SZ + t)*rowStride + (size_t)dir*dirOffset + tid], hnew);
    }
    __syncthreads();
    ir=nir; iz=niz; inn=ninn;
  }
}

// ---------------- kernel 5: ln0 ----------------
__global__ void ln0_kernel(const float* __restrict__ h2, const float* __restrict__ g,
                           const float* __restrict__ bt, float* __restrict__ out_ln){
  int idx = blockIdx.x*blockDim.x + threadIdx.x;
  if (idx >= B_SZ*8*L_SZ) return;
  int t = idx % L_SZ; int bn = idx / L_SZ; int n = bn & 7; int b = bn >> 3;
  const float* f0 = h2 + (size_t)(b*L_SZ+t)*HIDN + n*16;
  const float* f1 = f0 + (size_t)M_TOK*HIDN;
  float v[16]; float s = 0.f;
  #pragma unroll
  for (int d=0;d<16;d++){ v[d] = f0[d] + f1[d]; s += v[d]; }
  float mu = s*(1.f/16.f);
  float q = 0.f;
  #pragma unroll
  for (int d=0;d<16;d++){ float df = v[d]-mu; q += df*df; }
  float rs = rsqrtf(q*(1.f/16.f) + 1e-5f);
  float* o = out_ln + (size_t)idx*16;
  #pragma unroll
  for (int d=0;d<16;d++) o[d] = (v[d]-mu)*rs*g[d] + bt[d];
}

// ---------------- kernel 6: capsule conv v2 ----------------
// in [B][NC][HIN][16(a*4+x)], w [3][NC][4(x)][4(d)][32(m)], out [B][32][HOUT][16(a*4+d)]
// block: 128 threads = (m = tid>>2, d = tid&3); 4 h-positions.
// Weights read per-thread directly from global (no reuse across threads).
// in_s stored transposed to [x*4+a] so inner reads are float4 broadcasts.
template<int NC, int S>
__global__ __launch_bounds__(128) void caps_conv_kernel(
    const float* __restrict__ in, const float* __restrict__ w,
    const float* __restrict__ gam, const float* __restrict__ bet,
    float* __restrict__ out, int HIN, int HOUT, float inv_m)
{
  constexpr int NR = 3*S + 3;          // rows spanned by 4 outputs
  constexpr int TOT = 8*NR*16;
  __shared__ float in_s[8][NR*16];
  int b = blockIdx.y;
  int h0 = blockIdx.x*4;
  int tid = threadIdx.x;
  int m = tid >> 2, d = tid & 3;
  int row0 = h0 * S;
  float acc[4][4] = {{0.f}};           // [hh][a]

  #pragma unroll
  for (int ch=0; ch<NC/8; ++ch){
    int n0 = ch*8;
    // stage inputs with x<->a transpose; dest q = x*4+a, src = a*4+x
    for (int i=tid; i<TOT; i+=128){
      int nn = i/(NR*16); int rem = i - nn*NR*16; int rr = rem>>4; int q = rem&15;
      int x = q>>2, a = q&3;
      int rw = row0 + rr;
      float v = 0.f;
      if (rw < HIN) v = in[((size_t)(b*NC + n0 + nn)*HIN + rw)*16 + a*4 + x];
      in_s[nn][rr*16 + q] = v;
    }
    __syncthreads();
    #pragma unroll
    for (int k=0;k<3;k++)
      #pragma unroll
      for (int nn=0;nn<8;nn++){
        const float* wp = w + ((size_t)(k*NC + n0 + nn)*16 + d)*32 + m;  // x stride = 128
        float wv0 = wp[0], wv1 = wp[128], wv2 = wp[256], wv3 = wp[384];
        #pragma unroll
        for (int hh=0;hh<4;hh++){
          const float* ip = &in_s[nn][(hh*S + k)*16];
          float4 i0 = *(const float4*)(ip+0);
          float4 i1 = *(const float4*)(ip+4);
          float4 i2 = *(const float4*)(ip+8);
          float4 i3 = *(const float4*)(ip+12);
          acc[hh][0] += wv0*i0.x + wv1*i1.x + wv2*i2.x + wv3*i3.x;
          acc[hh][1] += wv0*i0.y + wv1*i1.y + wv2*i2.y + wv3*i3.y;
          acc[hh][2] += wv0*i0.z + wv1*i1.z + wv2*i2.z + wv3*i3.z;
          acc[hh][3] += wv0*i0.w + wv1*i1.w + wv2*i2.w + wv3*i3.w;
        }
      }
    __syncthreads();
  }

  float gv[4], bv[4];
  #pragma unroll
  for (int a=0;a<4;a++){ gv[a]=gam[a*4+d]; bv[a]=bet[a*4+d]; }
  for (int hh=0; hh<4; ++hh){
    int h = h0+hh;
    if (h >= HOUT) break;       // uniform across block
    float s = 0.f;
    #pragma unroll
    for (int a=0;a<4;a++){ acc[hh][a] *= inv_m; s += acc[hh][a]; }
    s += __shfl_xor(s,1); s += __shfl_xor(s,2);
    float mu = s*(1.f/16.f);
    float q2 = 0.f;
    #pragma unroll
    for (int a=0;a<4;a++){ float df = acc[hh][a]-mu; q2 += df*df; }
    q2 += __shfl_xor(q2,1); q2 += __shfl_xor(q2,2);
    float rs = rsqrtf(q2*(1.f/16.f) + 1e-5f);
    float* op = out + ((size_t)(b*32+m)*HOUT + h)*16 + d;
    #pragma unroll
    for (int a=0;a<4;a++) op[a*4] = (acc[hh][a]-mu)*rs*gv[a] + bv[a];
  }
}

// ---------------- kernel 7: transpose wfc -> wT[n][m][d][x] ----------------
__global__ void transposeW_kernel(const float* __restrict__ wfc, float* __restrict__ wT){
  int idx = blockIdx.x*blockDim.x + threadIdx.x;
  if (idx >= NFC*240) return;
  int n = idx / 240; int r = idx - n*240;
  int m = r >> 4; int dd = (r >> 2) & 3; int xx = r & 3;
  wT[idx] = wfc[(size_t)((n*4+xx)*4+dd)*15 + m];
}

// ---------------- kernel 8: routing pass ----------------
template<int WITH_SM>
__global__ __launch_bounds__(256) void route_pass_kernel(
    const float* __restrict__ v2, const float* __restrict__ wT,
    const float* __restrict__ v3, float* __restrict__ part)
{
  int ch = blockIdx.x, b = blockIdx.y;
  int tid = threadIdx.x;
  int nloc = tid >> 4;
  int ad = tid & 15; int a = ad >> 2; int d = ad & 3;
  int n0 = ch*32;

  __shared__ float wTs[32*240];
  __shared__ float fis[32*16];
  __shared__ float v3s[240];
  __shared__ float accs[3840];

  for (int i=tid; i<1920; i+=256)
    ((float4*)wTs)[i] = ((const float4*)(wT + (size_t)n0*240))[i];
  for (int i=tid; i<128; i+=256)
    ((float4*)fis)[i] = ((const float4*)(v2 + ((size_t)b*NFC + n0)*16))[i];
  if (WITH_SM && tid < 240) v3s[tid] = v3[(size_t)b*240 + tid];
  __syncthreads();

  float acc[15];
  #pragma unroll
  for (int m=0;m<15;m++) acc[m]=0.f;

  #pragma unroll
  for (int i=0;i<2;i++){
    int nl = nloc*2 + i;
    float4 fv = *(const float4*)&fis[nl*16 + a*4];
    float votes[15], lg[15];
    #pragma unroll
    for (int m=0;m<15;m++){
      float4 wv = *(const float4*)&wTs[nl*240 + m*16 + d*4];
      float vt = fv.x*wv.x + fv.y*wv.y + fv.z*wv.z + fv.w*wv.w;
      votes[m] = vt;
      if (WITH_SM){
        float p = vt * v3s[m*16 + ad];
        p += __shfl_xor(p,1); p += __shfl_xor(p,2);
        p += __shfl_xor(p,4); p += __shfl_xor(p,8);
        lg[m] = p * 0.25f;
      }
    }
    if (WITH_SM){
      float mx = lg[0];
      #pragma unroll
      for (int m=1;m<15;m++) mx = fmaxf(mx, lg[m]);
      float se = 0.f;
      #pragma unroll
      for (int m=0;m<15;m++){ lg[m] = __expf(lg[m]-mx); se += lg[m]; }
      float inv = 1.f/se;
      float s2 = 0.f;
      #pragma unroll
      for (int m=0;m<15;m++){ lg[m] *= inv; s2 += lg[m]; }
      float inv2 = 1.f/(s2 + 1e-10f);
      #pragma unroll
      for (int m=0;m<15;m++) acc[m] += lg[m]*inv2*votes[m];
    } else {
      #pragma unroll
      for (int m=0;m<15;m++) acc[m] += votes[m]*(1.f/15.f);
    }
  }
  #pragma unroll
  for (int m=0;m<15;m++) accs[(m*16+ad)*16 + nloc] = acc[m];
  __syncthreads();
  if (tid < 240){
    float s = 0.f;
    #pragma unroll
    for (int k=0;k<16;k++) s += accs[tid*16 + k];
    part[((size_t)b*NCH + ch)*240 + tid] = s;
  }
}

// ---------------- kernel 9: reduce partials -> LN -> v3 ----------------
__global__ __launch_bounds__(240) void reduce_v3_kernel(
    const float* __restrict__ part, const float* __restrict__ g,
    const float* __restrict__ bt, float* __restrict__ v3)
{
  int b = blockIdx.x; int tid = threadIdx.x;
  int ad = tid & 15;
  float s = 0.f;
  for (int ch=0; ch<NCH; ++ch) s += part[((size_t)b*NCH + ch)*240 + tid];
  float tot = s;
  tot += __shfl_xor(tot,1); tot += __shfl_xor(tot,2);
  tot += __shfl_xor(tot,4); tot += __shfl_xor(tot,8);
  float mu = tot*(1.f/16.f);
  float df = s - mu;
  float q = df*df;
  q += __shfl_xor(q,1); q += __shfl_xor(q,2);
  q += __shfl_xor(q,4); q += __shfl_xor(q,8);
  float rs = rsqrtf(q*(1.f/16.f) + 1e-5f);
  v3[(size_t)b*240 + tid] = df*rs*g[ad] + bt[ad];
}

// ---------------- kernel 10: reduce partials -> LN -> norm head -> out ----------------
__global__ __launch_bounds__(240) void reduce_out_kernel(
    const float* __restrict__ part, const float* __restrict__ g,
    const float* __restrict__ bt, float* __restrict__ out)
{
  int b = blockIdx.x; int tid = threadIdx.x;
  int m = tid >> 4; int ad = tid & 15;
  float s = 0.f;
  for (int ch=0; ch<NCH; ++ch) s += part[((size_t)b*NCH + ch)*240 + tid];
  float tot = s;
  tot += __shfl_xor(tot,1); tot += __shfl_xor(tot,2);
  tot += __shfl_xor(tot,4); tot += __shfl_xor(tot,8);
  float mu = tot*(1.f/16.f);
  float df = s - mu;
  float q = df*df;
  q += __shfl_xor(q,1); q += __shfl_xor(q,2);
  q += __shfl_xor(q,4); q += __shfl_xor(q,8);
  float rs = rsqrtf(q*(1.f/16.f) + 1e-5f);
  float v = df*rs*g[ad] + bt[ad];
  float q2 = v*v;
  q2 += __shfl_xor(q2,1); q2 += __shfl_xor(q2,2);
  q2 += __shfl_xor(q2,4); q2 += __shfl_xor(q2,8);
  if (ad == 0) out[(size_t)b*15 + m] = q2/(1.f+q2);
}

// =================================================================================
extern "C" void kernel_launch(void* const* d_in, const int* in_sizes, int n_in,
                              void* d_out, int out_size, void* d_ws, size_t ws_size,
                              hipStream_t stream) {
  const float* code     = (const float*)d_in[0];
  const float* codebook = (const float*)d_in[1];
  const float* w_ih0    = (const float*)d_in[2];
  const float* w_hh0    = (const float*)d_in[3];
  const float* b_ih0    = (const float*)d_in[4];
  const float* b_hh0    = (const float*)d_in[5];
  const float* w_ih1    = (const float*)d_in[6];
  const float* w_hh1    = (const float*)d_in[7];
  const float* b_ih1    = (const float*)d_in[8];
  const float* b_hh1    = (const float*)d_in[9];
  const float* ln0g     = (const float*)d_in[10];
  const float* ln0b     = (const float*)d_in[11];
  const float* w1       = (const float*)d_in[12];
  const float* ln1g     = (const float*)d_in[13];
  const float* ln1b     = (const float*)d_in[14];
  const float* w2       = (const float*)d_in[15];
  const float* ln2g     = (const float*)d_in[16];
  const float* ln2b     = (const float*)d_in[17];
  const float* wfc      = (const float*)d_in[18];
  const float* lnfg     = (const float*)d_in[19];
  const float* lnfb     = (const float*)d_in[20];
  const int*   x        = (const int*)d_in[21];
  float* out = (float*)d_out;
  float* ws  = (float*)d_ws;

  float* gi   = ws + 0;
  float* v1   = ws + 0;
  float* v2b  = ws + 4849664;
  float* wT   = ws + 9568256;
  float* part = ws + 10121216;
  __hip_bfloat16* h1b = (__hip_bfloat16*)(ws + 14745600);
  float* h2   = ws + 17203200;
  float* c_buf= ws + 17203200;
  float* out_ln = ws + 22118400;
  __hip_bfloat16* A0b = (__hip_bfloat16*)(ws + 22118400);
  __hip_bfloat16* W0b = (__hip_bfloat16*)(ws + 24576000);
  __hip_bfloat16* W1b = (__hip_bfloat16*)(ws + 24637440);
  float* v3   = ws + 24735744;

  softmax_c_kernel<<<(M_TOK*8 + 255)/256, 256, 0, stream>>>(code, x, c_buf);
  embed_bf16_kernel<<<(M_TOK*160 + 255)/256, 256, 0, stream>>>(c_buf, codebook, A0b, 160);
  convW_kernel<<<(768*160 + 255)/256, 256, 0, stream>>>(w_ih0, W0b, 768, 150, 160);
  convW_kernel<<<(768*256 + 255)/256, 256, 0, stream>>>(w_ih1, W1b, 768, 256, 256);
  gemm_mfma_kernel<<<dim3(6,150), 256, 0, stream>>>(A0b, W0b, b_ih0, gi, 160);
  gru_scan_kernel<__hip_bfloat16><<<256, 768, 0, stream>>>(gi, w_hh0, b_hh0, h1b, 256, (size_t)128);
  gemm_mfma_kernel<<<dim3(6,150), 256, 0, stream>>>(h1b, W1b, b_ih1, gi, 256);
  gru_scan_kernel<float><<<256, 768, 0, stream>>>(gi, w_hh1, b_hh1, h2, 128, (size_t)M_TOK*HIDN);
  ln0_kernel<<<(B_SZ*8*L_SZ + 255)/256, 256, 0, stream>>>(h2, ln0g, ln0b, out_ln);
  caps_conv_kernel<8,2><<<dim3(19,B_SZ), 128, 0, stream>>>(out_ln, w1, ln1g, ln1b, v1, 150, 74, 1.f/32.f);
  caps_conv_kernel<32,1><<<dim3(18,B_SZ), 128, 0, stream>>>(v1, w2, ln2g, ln2b, v2b, 74, 72, 1.f/32.f);
  transposeW_kernel<<<(NFC*240 + 255)/256, 256, 0, stream>>>(wfc, wT);
  route_pass_kernel<0><<<dim3(NCH,B_SZ), 256, 0, stream>>>(v2b, wT, nullptr, part);
  reduce_v3_kernel<<<B_SZ, 240, 0, stream>>>(part, lnfg, lnfb, v3);
  route_pass_kernel<1><<<dim3(NCH,B_SZ), 256, 0, stream>>>(v2b, wT, v3, part);
  reduce_out_kernel<<<B_SZ, 240, 0, stream>>>(part, lnfg, lnfb, out);
}

// Round 5
// 584.020 us; speedup vs baseline: 9.2569x; 9.2569x over previous
//
#include <hip/hip_runtime.h>
#include <hip/hip_bf16.h>
#include <cstdint>

// Model constants
#define B_SZ 128
#define L_SZ 150
#define E_SZ 150
#define HIDN 128
#define M_TOK (B_SZ*L_SZ)   // 19200
#define G3 384              // 3*HID gates
#define NFC 2304            // capsule-FC input count
#define NCH 72              // n-chunks per b (32 n each)

typedef __attribute__((ext_vector_type(8))) short bf16x8;
typedef __attribute__((ext_vector_type(4))) float f32x4;

__device__ __forceinline__ float sigm(float x){ return 1.f/(1.f+__expf(-x)); }

__device__ __forceinline__ void storeval(float* p, float v){ *p = v; }
__device__ __forceinline__ void storeval(__hip_bfloat16* p, float v){ *p = __float2bfloat16(v); }

// ---------------- kernel 1: c[t][32] = softmax over last-4 of code[x[t]] ----------------
__global__ void softmax_c_kernel(const float* __restrict__ code, const int* __restrict__ x,
                                 float* __restrict__ c){
  int idx = blockIdx.x*blockDim.x + threadIdx.x;
  if (idx >= M_TOK*8) return;
  int t = idx >> 3, j = idx & 7;
  int tok = x[t];
  const float* p = code + ((size_t)tok*32 + j*4);
  float a0=p[0],a1=p[1],a2=p[2],a3=p[3];
  float mx = fmaxf(fmaxf(a0,a1),fmaxf(a2,a3));
  float e0=__expf(a0-mx),e1=__expf(a1-mx),e2=__expf(a2-mx),e3=__expf(a3-mx);
  float inv = 1.f/(e0+e1+e2+e3);
  float* q = c + ((size_t)t*32 + j*4);
  q[0]=e0*inv; q[1]=e1*inv; q[2]=e2*inv; q[3]=e3*inv;
}

// ---------------- kernel 2: emb bf16 padded ----------------
__global__ void embed_bf16_kernel(const float* __restrict__ c, const float* __restrict__ cb,
                                  __hip_bfloat16* __restrict__ A0, int Kp){
  int idx = blockIdx.x*blockDim.x + threadIdx.x;
  if (idx >= M_TOK*160) return;
  int t = idx / 160; int e = idx - t*160;
  float acc = 0.f;
  if (e < E_SZ){
    const float* cr = c + (size_t)t*32;
    #pragma unroll
    for (int i=0;i<32;i++) acc += cr[i]*cb[i*E_SZ + e];
  }
  A0[(size_t)t*Kp + e] = __float2bfloat16(acc);
}

// ---------------- weight fp32->bf16 (K-padded) ----------------
__global__ void convW_kernel(const float* __restrict__ src, __hip_bfloat16* __restrict__ dst,
                             int N, int K, int Kp){
  int idx = blockIdx.x*blockDim.x + threadIdx.x;
  if (idx >= N*Kp) return;
  int n = idx / Kp; int k = idx - n*Kp;
  float v = (k < K) ? src[(size_t)n*K + k] : 0.f;
  dst[idx] = __float2bfloat16(v);
}

// ---------------- capsule-conv weight prep: dst[j=(m*4+d)][k*NCAPS*4 + n*4 + x] ----------------
__global__ void convWc_kernel(const float* __restrict__ w, __hip_bfloat16* __restrict__ dst,
                              int NCAPS){
  int KP = 12*NCAPS;
  int idx = blockIdx.x*blockDim.x + threadIdx.x;
  if (idx >= 128*KP) return;
  int j = idx / KP; int rem = idx - j*KP;
  int k = rem/(4*NCAPS); int r2 = rem - k*4*NCAPS; int n = r2>>2; int xx = r2&3;
  int m = j>>2, d = j&3;
  dst[idx] = __float2bfloat16(w[(size_t)(((k*NCAPS+n)*4+xx)*4+d)*32 + m]);
}

// ---------------- kernel 3: MFMA GEMM (input projections) ----------------
__global__ __launch_bounds__(256) void gemm_mfma_kernel(
    const __hip_bfloat16* __restrict__ A, const __hip_bfloat16* __restrict__ W,
    const float* __restrict__ bias, float* __restrict__ out, int Kp)
{
  __shared__ __hip_bfloat16 As[128*32];
  __shared__ __hip_bfloat16 Bs[128*32];
  int tid = threadIdx.x;
  int m0 = blockIdx.y*128, n0 = blockIdx.x*128;
  int lane = tid & 63, wid = tid >> 6;
  int wr = wid >> 1, wc = wid & 1;
  int srow = tid >> 2, scol = (tid & 3) * 8;

  f32x4 acc[4][4];
  #pragma unroll
  for (int i=0;i<4;i++)
    #pragma unroll
    for (int j=0;j<4;j++) acc[i][j] = (f32x4){0.f,0.f,0.f,0.f};

  int r = lane & 15, kq = (lane >> 4) * 8;

  for (int k0 = 0; k0 < Kp; k0 += 32){
    __builtin_amdgcn_global_load_lds(
      (const __attribute__((address_space(1))) void*)(A + (size_t)(m0+srow)*Kp + k0 + scol),
      (__attribute__((address_space(3))) void*)(As + tid*8), 16, 0, 0);
    __builtin_amdgcn_global_load_lds(
      (const __attribute__((address_space(1))) void*)(A + (size_t)(m0+64+srow)*Kp + k0 + scol),
      (__attribute__((address_space(3))) void*)(As + 2048 + tid*8), 16, 0, 0);
    __builtin_amdgcn_global_load_lds(
      (const __attribute__((address_space(1))) void*)(W + (size_t)(n0+srow)*Kp + k0 + scol),
      (__attribute__((address_space(3))) void*)(Bs + tid*8), 16, 0, 0);
    __builtin_amdgcn_global_load_lds(
      (const __attribute__((address_space(1))) void*)(W + (size_t)(n0+64+srow)*Kp + k0 + scol),
      (__attribute__((address_space(3))) void*)(Bs + 2048 + tid*8), 16, 0, 0);
    __syncthreads();

    bf16x8 aF[4], bF[4];
    #pragma unroll
    for (int mi=0;mi<4;mi++) aF[mi] = *(const bf16x8*)(As + (wr*64 + mi*16 + r)*32 + kq);
    #pragma unroll
    for (int nj=0;nj<4;nj++) bF[nj] = *(const bf16x8*)(Bs + (wc*64 + nj*16 + r)*32 + kq);
    #pragma unroll
    for (int mi=0;mi<4;mi++)
      #pragma unroll
      for (int nj=0;nj<4;nj++)
        acc[mi][nj] = __builtin_amdgcn_mfma_f32_16x16x32_bf16(aF[mi], bF[nj], acc[mi][nj], 0, 0, 0);
    __syncthreads();
  }

  #pragma unroll
  for (int nj=0;nj<4;nj++){
    int n = n0 + wc*64 + nj*16 + (lane & 15);
    int dir = (n >= G3) ? 1 : 0; int g = n - dir*G3;
    float bv = bias[n];
    #pragma unroll
    for (int mi=0;mi<4;mi++){
      #pragma unroll
      for (int r2=0;r2<4;r2++){
        int m = m0 + wr*64 + mi*16 + (lane>>4)*4 + r2;
        out[((size_t)dir*M_TOK + m)*G3 + g] = acc[mi][nj][r2] + bv;
      }
    }
  }
}

// ---------------- kernel 4: GRU scan (768 threads, K-split 2, gi prefetch) ----------------
template <typename OT>
__global__ __launch_bounds__(768) void gru_scan_kernel(
    const float* __restrict__ gi, const float* __restrict__ whh,
    const float* __restrict__ bhh, OT* __restrict__ out, int rowStride, size_t dirOffset)
{
  int bx = blockIdx.x; int dir = bx>>7; int b = bx&127;
  int tid = threadIdx.x;
  int half = (tid >= 384) ? 1 : 0;
  int row = tid - half*384;
  __shared__ float s_h[128];
  __shared__ float s_part[2][384];
  float4 w[16];
  const float4* wrow = (const float4*)(whh + (size_t)(dir*G3 + row)*HIDN + half*64);
  #pragma unroll
  for (int i=0;i<16;i++) w[i] = wrow[i];
  float bias = (half==0) ? bhh[dir*G3 + row] : 0.f;
  if (tid < 128) s_h[tid] = 0.f;
  const float* gib = gi + ((size_t)dir*M_TOK + (size_t)b*L_SZ)*G3;
  float ir=0.f, iz=0.f, inn=0.f;
  {
    int t0 = dir ? (L_SZ-1) : 0;
    if (tid < 128){
      const float* gr = gib + (size_t)t0*G3;
      ir = gr[tid]; iz = gr[128+tid]; inn = gr[256+tid];
    }
  }
  __syncthreads();
  for (int s=0; s<L_SZ; ++s){
    int t = dir ? (L_SZ-1 - s) : s;
    const float4* h4 = ((const float4*)s_h) + half*16;
    float p0=bias, p1=0.f;
    #pragma unroll
    for (int i=0;i<16;i+=2){
      float4 ha=h4[i], hb=h4[i+1];
      p0 += w[i].x*ha.x + w[i].y*ha.y + w[i].z*ha.z + w[i].w*ha.w;
      p1 += w[i+1].x*hb.x + w[i+1].y*hb.y + w[i+1].z*hb.z + w[i+1].w*hb.w;
    }
    s_part[half][row] = p0+p1;
    float nir=0.f, niz=0.f, ninn=0.f;
    if (tid < 128 && s+1 < L_SZ){
      int tn = dir ? (t-1) : (t+1);
      const float* gr = gib + (size_t)tn*G3;
      nir = gr[tid]; niz = gr[128+tid]; ninn = gr[256+tid];
    }
    __syncthreads();
    if (tid < 128){
      float hr = s_part[0][tid]     + s_part[1][tid];
      float hz = s_part[0][128+tid] + s_part[1][128+tid];
      float hn = s_part[0][256+tid] + s_part[1][256+tid];
      float rr = sigm(ir+hr);
      float zz = sigm(iz+hz);
      float xn = inn + rr*hn;
      float e2 = __expf(2.f*xn);
      float nn = 1.f - 2.f/(e2+1.f);
      float hnew = (1.f-zz)*nn + zz*s_h[tid];
      s_h[tid] = hnew;
      storeval(&out[(size_t)(b*L_SZ + t)*rowStride + (size_t)dir*dirOffset + tid], hnew);
    }
    __syncthreads();
    ir=nir; iz=niz; inn=ninn;
  }
}

// ---------------- kernel 5: ln0 -> in_t0[b][t][a][n][x] bf16 ----------------
__global__ void ln0_kernel(const float* __restrict__ h2, const float* __restrict__ g,
                           const float* __restrict__ bt, __hip_bfloat16* __restrict__ in_t0){
  int idx = blockIdx.x*blockDim.x + threadIdx.x;
  if (idx >= B_SZ*8*L_SZ) return;
  int t = idx % L_SZ; int bn = idx / L_SZ; int n = bn & 7; int b = bn >> 3;
  const float* f0 = h2 + (size_t)(b*L_SZ+t)*HIDN + n*16;
  const float* f1 = f0 + (size_t)M_TOK*HIDN;
  float v[16]; float s = 0.f;
  #pragma unroll
  for (int d=0;d<16;d++){ v[d] = f0[d] + f1[d]; s += v[d]; }
  float mu = s*(1.f/16.f);
  float q = 0.f;
  #pragma unroll
  for (int d=0;d<16;d++){ float df = v[d]-mu; q += df*df; }
  float rs = rsqrtf(q*(1.f/16.f) + 1e-5f);
  __hip_bfloat16* o = in_t0 + (size_t)b*19200 + t*128 + n*4;
  #pragma unroll
  for (int dd=0;dd<16;dd++){
    int a = dd>>2, xx = dd&3;
    o[a*32 + xx] = __float2bfloat16((v[dd]-mu)*rs*g[dd] + bt[dd]);
  }
}

// ---------------- kernel 6: capsule conv as MFMA GEMM with fused LN epilogue ----------------
// CONV=1: A=in_t0 [b][150][4][8][4] bf16, W=[128][96], out v1_t bf16 [row=(b*74+h)*4+a][j=m*4+d]
// CONV=2: A=v1_t  [b][74][4][32][4] bf16, W=[128][384], out v2f fp32 [b][m*72+h][a*4+d]
template<int CONV>
__global__ __launch_bounds__(256) void caps_mfma_kernel(
    const __hip_bfloat16* __restrict__ A, const __hip_bfloat16* __restrict__ W,
    const float* __restrict__ gam, const float* __restrict__ bet,
    void* __restrict__ outv)
{
  constexpr int KP   = (CONV==1) ? 96 : 384;
  constexpr int KTAP = (CONV==1) ? 32 : 128;   // K per tap; also = a-stride
  constexpr int S    = (CONV==1) ? 2 : 1;
  constexpr int H    = (CONV==1) ? 74 : 72;
  constexpr int RSTR = (CONV==1) ? 128 : 512;  // row(t) stride in elements
  constexpr int BSTR = (CONV==1) ? 19200 : 37888;
  __shared__ __hip_bfloat16 As[128*32];
  __shared__ __hip_bfloat16 Bs[128*32];
  int tid = threadIdx.x;
  int m0 = blockIdx.x*128;
  int lane = tid&63, wid = tid>>6;
  int wr = wid>>1, wc = wid&1;
  int srow = tid>>2, scol = (tid&3)*8;

  // staging row -> gathered global base (per-lane source is allowed for global_load_lds)
  int row1 = m0 + srow, row2 = row1 + 64;
  int bh1 = row1>>2, a1 = row1&3; int b1 = bh1/H, h1 = bh1 - b1*H;
  int bh2 = row2>>2, a2 = row2&3; int b2 = bh2/H, h2_ = bh2 - b2*H;
  const __hip_bfloat16* arow1 = A + (size_t)b1*BSTR + (size_t)(h1*S)*RSTR + a1*KTAP;
  const __hip_bfloat16* arow2 = A + (size_t)b2*BSTR + (size_t)(h2_*S)*RSTR + a2*KTAP;

  f32x4 acc[4][4];
  #pragma unroll
  for (int i=0;i<4;i++)
    #pragma unroll
    for (int j=0;j<4;j++) acc[i][j] = (f32x4){0.f,0.f,0.f,0.f};

  int r = lane&15, kq = (lane>>4)*8;

  for (int k0=0; k0<KP; k0+=32){
    int tap = k0/KTAP;
    int off = k0 - tap*KTAP + scol;
    __builtin_amdgcn_global_load_lds(
      (const __attribute__((address_space(1))) void*)(arow1 + tap*RSTR + off),
      (__attribute__((address_space(3))) void*)(As + tid*8), 16, 0, 0);
    __builtin_amdgcn_global_load_lds(
      (const __attribute__((address_space(1))) void*)(arow2 + tap*RSTR + off),
      (__attribute__((address_space(3))) void*)(As + 2048 + tid*8), 16, 0, 0);
    __builtin_amdgcn_global_load_lds(
      (const __attribute__((address_space(1))) void*)(W + (size_t)srow*KP + k0 + scol),
      (__attribute__((address_space(3))) void*)(Bs + tid*8), 16, 0, 0);
    __builtin_amdgcn_global_load_lds(
      (const __attribute__((address_space(1))) void*)(W + (size_t)(64+srow)*KP + k0 + scol),
      (__attribute__((address_space(3))) void*)(Bs + 2048 + tid*8), 16, 0, 0);
    __syncthreads();

    bf16x8 aF[4], bF[4];
    #pragma unroll
    for (int mi=0;mi<4;mi++) aF[mi] = *(const bf16x8*)(As + (wr*64 + mi*16 + r)*32 + kq);
    #pragma unroll
    for (int nj=0;nj<4;nj++) bF[nj] = *(const bf16x8*)(Bs + (wc*64 + nj*16 + r)*32 + kq);
    #pragma unroll
    for (int mi=0;mi<4;mi++)
      #pragma unroll
      for (int nj=0;nj<4;nj++)
        acc[mi][nj] = __builtin_amdgcn_mfma_f32_16x16x32_bf16(aF[mi], bF[nj], acc[mi][nj], 0, 0, 0);
    __syncthreads();
  }

  // fused LN epilogue: per lane j=(m,d) fixed, 4 regs = a=0..3 of one (b,h).
  // LN group (a,d): a-sum in-register, d-sum via shfl_xor(1,2) across the 4m..4m+3 lanes.
  #pragma unroll
  for (int mi=0;mi<4;mi++)
    #pragma unroll
    for (int nj=0;nj<4;nj++){
      int jj = wc*64 + nj*16 + (lane&15);
      int rowb = m0 + wr*64 + mi*16 + (lane>>4)*4;
      float vv[4];
      #pragma unroll
      for (int r2=0;r2<4;r2++) vv[r2] = acc[mi][nj][r2]*(1.f/32.f);
      float s = vv[0]+vv[1]+vv[2]+vv[3];
      s += __shfl_xor(s,1); s += __shfl_xor(s,2);
      float mu = s*(1.f/16.f);
      float q = 0.f;
      #pragma unroll
      for (int r2=0;r2<4;r2++){ float df = vv[r2]-mu; q += df*df; }
      q += __shfl_xor(q,1); q += __shfl_xor(q,2);
      float rs = rsqrtf(q*(1.f/16.f) + 1e-5f);
      int d = jj&3;
      #pragma unroll
      for (int r2=0;r2<4;r2++){
        float o = (vv[r2]-mu)*rs*gam[r2*4+d] + bet[r2*4+d];
        if constexpr (CONV==1){
          ((__hip_bfloat16*)outv)[(size_t)(rowb+r2)*128 + jj] = __float2bfloat16(o);
        } else {
          int rw = rowb + r2; int bh = rw>>2, a = rw&3; int bb = bh/H, hh = bh - bb*H;
          ((float*)outv)[((size_t)bb*NFC + (jj>>2)*H + hh)*16 + a*4 + d] = o;
        }
      }
    }
}

// ---------------- kernel 7: transpose wfc -> wT[n][m][d][x] ----------------
__global__ void transposeW_kernel(const float* __restrict__ wfc, float* __restrict__ wT){
  int idx = blockIdx.x*blockDim.x + threadIdx.x;
  if (idx >= NFC*240) return;
  int n = idx / 240; int r = idx - n*240;
  int m = r >> 4; int dd = (r >> 2) & 3; int xx = r & 3;
  wT[idx] = wfc[(size_t)((n*4+xx)*4+dd)*15 + m];
}

// ---------------- kernel 8: routing pass ----------------
template<int WITH_SM>
__global__ __launch_bounds__(256) void route_pass_kernel(
    const float* __restrict__ v2, const float* __restrict__ wT,
    const float* __restrict__ v3, float* __restrict__ part)
{
  int ch = blockIdx.x, b = blockIdx.y;
  int tid = threadIdx.x;
  int nloc = tid >> 4;
  int ad = tid & 15; int a = ad >> 2; int d = ad & 3;
  int n0 = ch*32;

  __shared__ float wTs[32*240];
  __shared__ float fis[32*16];
  __shared__ float v3s[240];
  __shared__ float accs[3840];

  for (int i=tid; i<1920; i+=256)
    ((float4*)wTs)[i] = ((const float4*)(wT + (size_t)n0*240))[i];
  for (int i=tid; i<128; i+=256)
    ((float4*)fis)[i] = ((const float4*)(v2 + ((size_t)b*NFC + n0)*16))[i];
  if (WITH_SM && tid < 240) v3s[tid] = v3[(size_t)b*240 + tid];
  __syncthreads();

  float acc[15];
  #pragma unroll
  for (int m=0;m<15;m++) acc[m]=0.f;

  #pragma unroll
  for (int i=0;i<2;i++){
    int nl = nloc*2 + i;
    float4 fv = *(const float4*)&fis[nl*16 + a*4];
    float votes[15], lg[15];
    #pragma unroll
    for (int m=0;m<15;m++){
      float4 wv = *(const float4*)&wTs[nl*240 + m*16 + d*4];
      float vt = fv.x*wv.x + fv.y*wv.y + fv.z*wv.z + fv.w*wv.w;
      votes[m] = vt;
      if (WITH_SM){
        float p = vt * v3s[m*16 + ad];
        p += __shfl_xor(p,1); p += __shfl_xor(p,2);
        p += __shfl_xor(p,4); p += __shfl_xor(p,8);
        lg[m] = p * 0.25f;
      }
    }
    if (WITH_SM){
      float mx = lg[0];
      #pragma unroll
      for (int m=1;m<15;m++) mx = fmaxf(mx, lg[m]);
      float se = 0.f;
      #pragma unroll
      for (int m=0;m<15;m++){ lg[m] = __expf(lg[m]-mx); se += lg[m]; }
      float inv = 1.f/se;
      float s2 = 0.f;
      #pragma unroll
      for (int m=0;m<15;m++){ lg[m] *= inv; s2 += lg[m]; }
      float inv2 = 1.f/(s2 + 1e-10f);
      #pragma unroll
      for (int m=0;m<15;m++) acc[m] += lg[m]*inv2*votes[m];
    } else {
      #pragma unroll
      for (int m=0;m<15;m++) acc[m] += votes[m]*(1.f/15.f);
    }
  }
  #pragma unroll
  for (int m=0;m<15;m++) accs[(m*16+ad)*16 + nloc] = acc[m];
  __syncthreads();
  if (tid < 240){
    float s = 0.f;
    #pragma unroll
    for (int k=0;k<16;k++) s += accs[tid*16 + k];
    part[((size_t)b*NCH + ch)*240 + tid] = s;
  }
}

// ---------------- kernel 9: reduce partials -> LN -> v3 ----------------
__global__ __launch_bounds__(240) void reduce_v3_kernel(
    const float* __restrict__ part, const float* __restrict__ g,
    const float* __restrict__ bt, float* __restrict__ v3)
{
  int b = blockIdx.x; int tid = threadIdx.x;
  int ad = tid & 15;
  float s = 0.f;
  for (int ch=0; ch<NCH; ++ch) s += part[((size_t)b*NCH + ch)*240 + tid];
  float tot = s;
  tot += __shfl_xor(tot,1); tot += __shfl_xor(tot,2);
  tot += __shfl_xor(tot,4); tot += __shfl_xor(tot,8);
  float mu = tot*(1.f/16.f);
  float df = s - mu;
  float q = df*df;
  q += __shfl_xor(q,1); q += __shfl_xor(q,2);
  q += __shfl_xor(q,4); q += __shfl_xor(q,8);
  float rs = rsqrtf(q*(1.f/16.f) + 1e-5f);
  v3[(size_t)b*240 + tid] = df*rs*g[ad] + bt[ad];
}

// ---------------- kernel 10: reduce partials -> LN -> norm head -> out ----------------
__global__ __launch_bounds__(240) void reduce_out_kernel(
    const float* __restrict__ part, const float* __restrict__ g,
    const float* __restrict__ bt, float* __restrict__ out)
{
  int b = blockIdx.x; int tid = threadIdx.x;
  int m = tid >> 4; int ad = tid & 15;
  float s = 0.f;
  for (int ch=0; ch<NCH; ++ch) s += part[((size_t)b*NCH + ch)*240 + tid];
  float tot = s;
  tot += __shfl_xor(tot,1); tot += __shfl_xor(tot,2);
  tot += __shfl_xor(tot,4); tot += __shfl_xor(tot,8);
  float mu = tot*(1.f/16.f);
  float df = s - mu;
  float q = df*df;
  q += __shfl_xor(q,1); q += __shfl_xor(q,2);
  q += __shfl_xor(q,4); q += __shfl_xor(q,8);
  float rs = rsqrtf(q*(1.f/16.f) + 1e-5f);
  float v = df*rs*g[ad] + bt[ad];
  float q2 = v*v;
  q2 += __shfl_xor(q2,1); q2 += __shfl_xor(q2,2);
  q2 += __shfl_xor(q2,4); q2 += __shfl_xor(q2,8);
  if (ad == 0) out[(size_t)b*15 + m] = q2/(1.f+q2);
}

// =================================================================================
extern "C" void kernel_launch(void* const* d_in, const int* in_sizes, int n_in,
                              void* d_out, int out_size, void* d_ws, size_t ws_size,
                              hipStream_t stream) {
  const float* code     = (const float*)d_in[0];
  const float* codebook = (const float*)d_in[1];
  const float* w_ih0    = (const float*)d_in[2];
  const float* w_hh0    = (const float*)d_in[3];
  const float* b_ih0    = (const float*)d_in[4];
  const float* b_hh0    = (const float*)d_in[5];
  const float* w_ih1    = (const float*)d_in[6];
  const float* w_hh1    = (const float*)d_in[7];
  const float* b_ih1    = (const float*)d_in[8];
  const float* b_hh1    = (const float*)d_in[9];
  const float* ln0g     = (const float*)d_in[10];
  const float* ln0b     = (const float*)d_in[11];
  const float* w1       = (const float*)d_in[12];
  const float* ln1g     = (const float*)d_in[13];
  const float* ln1b     = (const float*)d_in[14];
  const float* w2       = (const float*)d_in[15];
  const float* ln2g     = (const float*)d_in[16];
  const float* ln2b     = (const float*)d_in[17];
  const float* wfc      = (const float*)d_in[18];
  const float* lnfg     = (const float*)d_in[19];
  const float* lnfb     = (const float*)d_in[20];
  const int*   x        = (const int*)d_in[21];
  float* out = (float*)d_out;
  float* ws  = (float*)d_ws;

  // workspace layout (float offsets), high-water ~99.2 MB
  float* gi   = ws + 0;                                    // dead after scan2
  __hip_bfloat16* v1t = (__hip_bfloat16*)(ws + 0);         // 4,849,664 bf16 (after scans)
  float* v2f  = ws + 4849664;                              // 4,718,592 f -> 9,568,256
  float* wT   = ws + 9568256;                              //   552,960 f -> 10,121,216
  float* part = ws + 10121216;                             // 2,211,840 f -> 12,333,056
  __hip_bfloat16* h1b = (__hip_bfloat16*)(ws + 14745600);  // 19200x256 bf16
  float* h2   = ws + 17203200;                             // 4,915,200 f
  float* c_buf= ws + 17203200;                             // aliases h2 (dead before scan2)
  __hip_bfloat16* in_t0 = (__hip_bfloat16*)(ws + 22118400);// 2,457,600 bf16
  __hip_bfloat16* A0b = (__hip_bfloat16*)(ws + 22118400);  // aliases in_t0 (dead after gemm0)
  __hip_bfloat16* W0b = (__hip_bfloat16*)(ws + 24576000);
  __hip_bfloat16* W1b = (__hip_bfloat16*)(ws + 24637440);
  float* v3   = ws + 24735744;                             //    30,720 f
  __hip_bfloat16* Wc1b = (__hip_bfloat16*)(ws + 24766464); //  12,288 bf16 -> +6,144 f
  __hip_bfloat16* Wc2b = (__hip_bfloat16*)(ws + 24772608); //  49,152 bf16 -> +24,576 f

  softmax_c_kernel<<<(M_TOK*8 + 255)/256, 256, 0, stream>>>(code, x, c_buf);
  embed_bf16_kernel<<<(M_TOK*160 + 255)/256, 256, 0, stream>>>(c_buf, codebook, A0b, 160);
  convW_kernel<<<(768*160 + 255)/256, 256, 0, stream>>>(w_ih0, W0b, 768, 150, 160);
  convW_kernel<<<(768*256 + 255)/256, 256, 0, stream>>>(w_ih1, W1b, 768, 256, 256);
  convWc_kernel<<<(128*96 + 255)/256, 256, 0, stream>>>(w1, Wc1b, 8);
  convWc_kernel<<<(128*384 + 255)/256, 256, 0, stream>>>(w2, Wc2b, 32);
  gemm_mfma_kernel<<<dim3(6,150), 256, 0, stream>>>(A0b, W0b, b_ih0, gi, 160);
  gru_scan_kernel<__hip_bfloat16><<<256, 768, 0, stream>>>(gi, w_hh0, b_hh0, h1b, 256, (size_t)128);
  gemm_mfma_kernel<<<dim3(6,150), 256, 0, stream>>>(h1b, W1b, b_ih1, gi, 256);
  gru_scan_kernel<float><<<256, 768, 0, stream>>>(gi, w_hh1, b_hh1, h2, 128, (size_t)M_TOK*HIDN);
  ln0_kernel<<<(B_SZ*8*L_SZ + 255)/256, 256, 0, stream>>>(h2, ln0g, ln0b, in_t0);
  // capsule convs as MFMA GEMMs with fused LN
  caps_mfma_kernel<1><<<296, 256, 0, stream>>>(in_t0, Wc1b, ln1g, ln1b, (void*)v1t);
  caps_mfma_kernel<2><<<288, 256, 0, stream>>>(v1t, Wc2b, ln2g, ln2b, (void*)v2f);
  transposeW_kernel<<<(NFC*240 + 255)/256, 256, 0, stream>>>(wfc, wT);
  route_pass_kernel<0><<<dim3(NCH,B_SZ), 256, 0, stream>>>(v2f, wT, nullptr, part);
  reduce_v3_kernel<<<B_SZ, 240, 0, stream>>>(part, lnfg, lnfb, v3);
  route_pass_kernel<1><<<dim3(NCH,B_SZ), 256, 0, stream>>>(v2f, wT, v3, part);
  reduce_out_kernel<<<B_SZ, 240, 0, stream>>>(part, lnfg, lnfb, out);
}

// Round 6
// 583.196 us; speedup vs baseline: 9.2700x; 1.0014x over previous
//
#include <hip/hip_runtime.h>
#include <hip/hip_bf16.h>
#include <cstdint>

// Model constants
#define B_SZ 128
#define L_SZ 150
#define E_SZ 150
#define HIDN 128
#define M_TOK (B_SZ*L_SZ)   // 19200
#define G3 384              // 3*HID gates
#define NFC 2304            // capsule-FC input count
#define NCH 72              // n-chunks per b (32 n each)

typedef __attribute__((ext_vector_type(8))) short bf16x8;
typedef __attribute__((ext_vector_type(4))) float f32x4;

__device__ __forceinline__ float sigm(float x){ return 1.f/(1.f+__expf(-x)); }

__device__ __forceinline__ void storeval(float* p, float v){ *p = v; }
__device__ __forceinline__ void storeval(__hip_bfloat16* p, float v){ *p = __float2bfloat16(v); }

// ---------------- kernel 1: c[t][32] = softmax over last-4 of code[x[t]] ----------------
__global__ void softmax_c_kernel(const float* __restrict__ code, const int* __restrict__ x,
                                 float* __restrict__ c){
  int idx = blockIdx.x*blockDim.x + threadIdx.x;
  if (idx >= M_TOK*8) return;
  int t = idx >> 3, j = idx & 7;
  int tok = x[t];
  const float* p = code + ((size_t)tok*32 + j*4);
  float a0=p[0],a1=p[1],a2=p[2],a3=p[3];
  float mx = fmaxf(fmaxf(a0,a1),fmaxf(a2,a3));
  float e0=__expf(a0-mx),e1=__expf(a1-mx),e2=__expf(a2-mx),e3=__expf(a3-mx);
  float inv = 1.f/(e0+e1+e2+e3);
  float* q = c + ((size_t)t*32 + j*4);
  q[0]=e0*inv; q[1]=e1*inv; q[2]=e2*inv; q[3]=e3*inv;
}

// ---------------- kernel 2: emb bf16 padded ----------------
__global__ void embed_bf16_kernel(const float* __restrict__ c, const float* __restrict__ cb,
                                  __hip_bfloat16* __restrict__ A0, int Kp){
  int idx = blockIdx.x*blockDim.x + threadIdx.x;
  if (idx >= M_TOK*160) return;
  int t = idx / 160; int e = idx - t*160;
  float acc = 0.f;
  if (e < E_SZ){
    const float* cr = c + (size_t)t*32;
    #pragma unroll
    for (int i=0;i<32;i++) acc += cr[i]*cb[i*E_SZ + e];
  }
  A0[(size_t)t*Kp + e] = __float2bfloat16(acc);
}

// ---------------- weight fp32->bf16 (K-padded) ----------------
__global__ void convW_kernel(const float* __restrict__ src, __hip_bfloat16* __restrict__ dst,
                             int N, int K, int Kp){
  int idx = blockIdx.x*blockDim.x + threadIdx.x;
  if (idx >= N*Kp) return;
  int n = idx / Kp; int k = idx - n*Kp;
  float v = (k < K) ? src[(size_t)n*K + k] : 0.f;
  dst[idx] = __float2bfloat16(v);
}

// ---------------- capsule-conv weight prep: dst[j=(m*4+d)][k*NCAPS*4 + n*4 + x] ----------------
__global__ void convWc_kernel(const float* __restrict__ w, __hip_bfloat16* __restrict__ dst,
                              int NCAPS){
  int KP = 12*NCAPS;
  int idx = blockIdx.x*blockDim.x + threadIdx.x;
  if (idx >= 128*KP) return;
  int j = idx / KP; int rem = idx - j*KP;
  int k = rem/(4*NCAPS); int r2 = rem - k*4*NCAPS; int n = r2>>2; int xx = r2&3;
  int m = j>>2, d = j&3;
  dst[idx] = __float2bfloat16(w[(size_t)(((k*NCAPS+n)*4+xx)*4+d)*32 + m]);
}

// ---------------- kernel 3: MFMA GEMM (input projections) ----------------
__global__ __launch_bounds__(256) void gemm_mfma_kernel(
    const __hip_bfloat16* __restrict__ A, const __hip_bfloat16* __restrict__ W,
    const float* __restrict__ bias, float* __restrict__ out, int Kp)
{
  __shared__ __hip_bfloat16 As[128*32];
  __shared__ __hip_bfloat16 Bs[128*32];
  int tid = threadIdx.x;
  int m0 = blockIdx.y*128, n0 = blockIdx.x*128;
  int lane = tid & 63, wid = tid >> 6;
  int wr = wid >> 1, wc = wid & 1;
  int srow = tid >> 2, scol = (tid & 3) * 8;

  f32x4 acc[4][4];
  #pragma unroll
  for (int i=0;i<4;i++)
    #pragma unroll
    for (int j=0;j<4;j++) acc[i][j] = (f32x4){0.f,0.f,0.f,0.f};

  int r = lane & 15, kq = (lane >> 4) * 8;

  for (int k0 = 0; k0 < Kp; k0 += 32){
    __builtin_amdgcn_global_load_lds(
      (const __attribute__((address_space(1))) void*)(A + (size_t)(m0+srow)*Kp + k0 + scol),
      (__attribute__((address_space(3))) void*)(As + tid*8), 16, 0, 0);
    __builtin_amdgcn_global_load_lds(
      (const __attribute__((address_space(1))) void*)(A + (size_t)(m0+64+srow)*Kp + k0 + scol),
      (__attribute__((address_space(3))) void*)(As + 2048 + tid*8), 16, 0, 0);
    __builtin_amdgcn_global_load_lds(
      (const __attribute__((address_space(1))) void*)(W + (size_t)(n0+srow)*Kp + k0 + scol),
      (__attribute__((address_space(3))) void*)(Bs + tid*8), 16, 0, 0);
    __builtin_amdgcn_global_load_lds(
      (const __attribute__((address_space(1))) void*)(W + (size_t)(n0+64+srow)*Kp + k0 + scol),
      (__attribute__((address_space(3))) void*)(Bs + 2048 + tid*8), 16, 0, 0);
    __syncthreads();

    bf16x8 aF[4], bF[4];
    #pragma unroll
    for (int mi=0;mi<4;mi++) aF[mi] = *(const bf16x8*)(As + (wr*64 + mi*16 + r)*32 + kq);
    #pragma unroll
    for (int nj=0;nj<4;nj++) bF[nj] = *(const bf16x8*)(Bs + (wc*64 + nj*16 + r)*32 + kq);
    #pragma unroll
    for (int mi=0;mi<4;mi++)
      #pragma unroll
      for (int nj=0;nj<4;nj++)
        acc[mi][nj] = __builtin_amdgcn_mfma_f32_16x16x32_bf16(aF[mi], bF[nj], acc[mi][nj], 0, 0, 0);
    __syncthreads();
  }

  #pragma unroll
  for (int nj=0;nj<4;nj++){
    int n = n0 + wc*64 + nj*16 + (lane & 15);
    int dir = (n >= G3) ? 1 : 0; int g = n - dir*G3;
    float bv = bias[n];
    #pragma unroll
    for (int mi=0;mi<4;mi++){
      #pragma unroll
      for (int r2=0;r2<4;r2++){
        int m = m0 + wr*64 + mi*16 + (lane>>4)*4 + r2;
        out[((size_t)dir*M_TOK + m)*G3 + g] = acc[mi][nj][r2] + bv;
      }
    }
  }
}

// ---------------- kernel 4: GRU scan (768 threads = 12 waves = 1 block/CU) ----------------
// __launch_bounds__(768, 3): 3 waves/SIMD min => VGPR budget ~170 so w[16] (64 VGPR)
// stays register-resident across all 150 steps. (R5 bug: no min-waves arg => 52 VGPR
// cap for 2-blocks/CU occupancy that never materializes at grid=256.)
template <typename OT>
__global__ __launch_bounds__(768, 3) void gru_scan_kernel(
    const float* __restrict__ gi, const float* __restrict__ whh,
    const float* __restrict__ bhh, OT* __restrict__ out, int rowStride, size_t dirOffset)
{
  int bx = blockIdx.x; int dir = bx>>7; int b = bx&127;
  int tid = threadIdx.x;
  int half = (tid >= 384) ? 1 : 0;
  int row = tid - half*384;
  __shared__ float s_h[128];
  __shared__ float s_part[2][384];
  float4 w[16];
  const float4* wrow = (const float4*)(whh + (size_t)(dir*G3 + row)*HIDN + half*64);
  #pragma unroll
  for (int i=0;i<16;i++) w[i] = wrow[i];
  float bias = (half==0) ? bhh[dir*G3 + row] : 0.f;
  if (tid < 128) s_h[tid] = 0.f;
  const float* gib = gi + ((size_t)dir*M_TOK + (size_t)b*L_SZ)*G3;
  float ir=0.f, iz=0.f, inn=0.f;
  {
    int t0 = dir ? (L_SZ-1) : 0;
    if (tid < 128){
      const float* gr = gib + (size_t)t0*G3;
      ir = gr[tid]; iz = gr[128+tid]; inn = gr[256+tid];
    }
  }
  __syncthreads();
  for (int s=0; s<L_SZ; ++s){
    int t = dir ? (L_SZ-1 - s) : s;
    const float4* h4 = ((const float4*)s_h) + half*16;
    float p0=bias, p1=0.f;
    #pragma unroll
    for (int i=0;i<16;i+=2){
      float4 ha=h4[i], hb=h4[i+1];
      p0 += w[i].x*ha.x + w[i].y*ha.y + w[i].z*ha.z + w[i].w*ha.w;
      p1 += w[i+1].x*hb.x + w[i+1].y*hb.y + w[i+1].z*hb.z + w[i+1].w*hb.w;
    }
    s_part[half][row] = p0+p1;
    float nir=0.f, niz=0.f, ninn=0.f;
    if (tid < 128 && s+1 < L_SZ){
      int tn = dir ? (t-1) : (t+1);
      const float* gr = gib + (size_t)tn*G3;
      nir = gr[tid]; niz = gr[128+tid]; ninn = gr[256+tid];
    }
    __syncthreads();
    if (tid < 128){
      float hr = s_part[0][tid]     + s_part[1][tid];
      float hz = s_part[0][128+tid] + s_part[1][128+tid];
      float hn = s_part[0][256+tid] + s_part[1][256+tid];
      float rr = sigm(ir+hr);
      float zz = sigm(iz+hz);
      float xn = inn + rr*hn;
      float e2 = __expf(2.f*xn);
      float nn = 1.f - 2.f/(e2+1.f);
      float hnew = (1.f-zz)*nn + zz*s_h[tid];
      s_h[tid] = hnew;
      storeval(&out[(size_t)(b*L_SZ + t)*rowStride + (size_t)dir*dirOffset + tid], hnew);
    }
    __syncthreads();
    ir=nir; iz=niz; inn=ninn;
  }
}

// ---------------- kernel 5: ln0 -> in_t0[b][t][a][n][x] bf16 ----------------
__global__ void ln0_kernel(const float* __restrict__ h2, const float* __restrict__ g,
                           const float* __restrict__ bt, __hip_bfloat16* __restrict__ in_t0){
  int idx = blockIdx.x*blockDim.x + threadIdx.x;
  if (idx >= B_SZ*8*L_SZ) return;
  int t = idx % L_SZ; int bn = idx / L_SZ; int n = bn & 7; int b = bn >> 3;
  const float* f0 = h2 + (size_t)(b*L_SZ+t)*HIDN + n*16;
  const float* f1 = f0 + (size_t)M_TOK*HIDN;
  float v[16]; float s = 0.f;
  #pragma unroll
  for (int d=0;d<16;d++){ v[d] = f0[d] + f1[d]; s += v[d]; }
  float mu = s*(1.f/16.f);
  float q = 0.f;
  #pragma unroll
  for (int d=0;d<16;d++){ float df = v[d]-mu; q += df*df; }
  float rs = rsqrtf(q*(1.f/16.f) + 1e-5f);
  __hip_bfloat16* o = in_t0 + (size_t)b*19200 + t*128 + n*4;
  #pragma unroll
  for (int dd=0;dd<16;dd++){
    int a = dd>>2, xx = dd&3;
    o[a*32 + xx] = __float2bfloat16((v[dd]-mu)*rs*g[dd] + bt[dd]);
  }
}

// ---------------- kernel 6: capsule conv as MFMA GEMM with fused LN epilogue ----------------
template<int CONV>
__global__ __launch_bounds__(256) void caps_mfma_kernel(
    const __hip_bfloat16* __restrict__ A, const __hip_bfloat16* __restrict__ W,
    const float* __restrict__ gam, const float* __restrict__ bet,
    void* __restrict__ outv)
{
  constexpr int KP   = (CONV==1) ? 96 : 384;
  constexpr int KTAP = (CONV==1) ? 32 : 128;
  constexpr int S    = (CONV==1) ? 2 : 1;
  constexpr int H    = (CONV==1) ? 74 : 72;
  constexpr int RSTR = (CONV==1) ? 128 : 512;
  constexpr int BSTR = (CONV==1) ? 19200 : 37888;
  __shared__ __hip_bfloat16 As[128*32];
  __shared__ __hip_bfloat16 Bs[128*32];
  int tid = threadIdx.x;
  int m0 = blockIdx.x*128;
  int lane = tid&63, wid = tid>>6;
  int wr = wid>>1, wc = wid&1;
  int srow = tid>>2, scol = (tid&3)*8;

  int row1 = m0 + srow, row2 = row1 + 64;
  int bh1 = row1>>2, a1 = row1&3; int b1 = bh1/H, h1 = bh1 - b1*H;
  int bh2 = row2>>2, a2 = row2&3; int b2 = bh2/H, h2_ = bh2 - b2*H;
  const __hip_bfloat16* arow1 = A + (size_t)b1*BSTR + (size_t)(h1*S)*RSTR + a1*KTAP;
  const __hip_bfloat16* arow2 = A + (size_t)b2*BSTR + (size_t)(h2_*S)*RSTR + a2*KTAP;

  f32x4 acc[4][4];
  #pragma unroll
  for (int i=0;i<4;i++)
    #pragma unroll
    for (int j=0;j<4;j++) acc[i][j] = (f32x4){0.f,0.f,0.f,0.f};

  int r = lane&15, kq = (lane>>4)*8;

  for (int k0=0; k0<KP; k0+=32){
    int tap = k0/KTAP;
    int off = k0 - tap*KTAP + scol;
    __builtin_amdgcn_global_load_lds(
      (const __attribute__((address_space(1))) void*)(arow1 + tap*RSTR + off),
      (__attribute__((address_space(3))) void*)(As + tid*8), 16, 0, 0);
    __builtin_amdgcn_global_load_lds(
      (const __attribute__((address_space(1))) void*)(arow2 + tap*RSTR + off),
      (__attribute__((address_space(3))) void*)(As + 2048 + tid*8), 16, 0, 0);
    __builtin_amdgcn_global_load_lds(
      (const __attribute__((address_space(1))) void*)(W + (size_t)srow*KP + k0 + scol),
      (__attribute__((address_space(3))) void*)(Bs + tid*8), 16, 0, 0);
    __builtin_amdgcn_global_load_lds(
      (const __attribute__((address_space(1))) void*)(W + (size_t)(64+srow)*KP + k0 + scol),
      (__attribute__((address_space(3))) void*)(Bs + 2048 + tid*8), 16, 0, 0);
    __syncthreads();

    bf16x8 aF[4], bF[4];
    #pragma unroll
    for (int mi=0;mi<4;mi++) aF[mi] = *(const bf16x8*)(As + (wr*64 + mi*16 + r)*32 + kq);
    #pragma unroll
    for (int nj=0;nj<4;nj++) bF[nj] = *(const bf16x8*)(Bs + (wc*64 + nj*16 + r)*32 + kq);
    #pragma unroll
    for (int mi=0;mi<4;mi++)
      #pragma unroll
      for (int nj=0;nj<4;nj++)
        acc[mi][nj] = __builtin_amdgcn_mfma_f32_16x16x32_bf16(aF[mi], bF[nj], acc[mi][nj], 0, 0, 0);
    __syncthreads();
  }

  #pragma unroll
  for (int mi=0;mi<4;mi++)
    #pragma unroll
    for (int nj=0;nj<4;nj++){
      int jj = wc*64 + nj*16 + (lane&15);
      int rowb = m0 + wr*64 + mi*16 + (lane>>4)*4;
      float vv[4];
      #pragma unroll
      for (int r2=0;r2<4;r2++) vv[r2] = acc[mi][nj][r2]*(1.f/32.f);
      float s = vv[0]+vv[1]+vv[2]+vv[3];
      s += __shfl_xor(s,1); s += __shfl_xor(s,2);
      float mu = s*(1.f/16.f);
      float q = 0.f;
      #pragma unroll
      for (int r2=0;r2<4;r2++){ float df = vv[r2]-mu; q += df*df; }
      q += __shfl_xor(q,1); q += __shfl_xor(q,2);
      float rs = rsqrtf(q*(1.f/16.f) + 1e-5f);
      int d = jj&3;
      #pragma unroll
      for (int r2=0;r2<4;r2++){
        float o = (vv[r2]-mu)*rs*gam[r2*4+d] + bet[r2*4+d];
        if constexpr (CONV==1){
          ((__hip_bfloat16*)outv)[(size_t)(rowb+r2)*128 + jj] = __float2bfloat16(o);
        } else {
          int rw = rowb + r2; int bh = rw>>2, a = rw&3; int bb = bh/H, hh = bh - bb*H;
          ((float*)outv)[((size_t)bb*NFC + (jj>>2)*H + hh)*16 + a*4 + d] = o;
        }
      }
    }
}

// ---------------- kernel 7: transpose wfc -> wT[n][m][d][x] ----------------
__global__ void transposeW_kernel(const float* __restrict__ wfc, float* __restrict__ wT){
  int idx = blockIdx.x*blockDim.x + threadIdx.x;
  if (idx >= NFC*240) return;
  int n = idx / 240; int r = idx - n*240;
  int m = r >> 4; int dd = (r >> 2) & 3; int xx = r & 3;
  wT[idx] = wfc[(size_t)((n*4+xx)*4+dd)*15 + m];
}

// ---------------- kernel 8: routing pass ----------------
template<int WITH_SM>
__global__ __launch_bounds__(256) void route_pass_kernel(
    const float* __restrict__ v2, const float* __restrict__ wT,
    const float* __restrict__ v3, float* __restrict__ part)
{
  int ch = blockIdx.x, b = blockIdx.y;
  int tid = threadIdx.x;
  int nloc = tid >> 4;
  int ad = tid & 15; int a = ad >> 2; int d = ad & 3;
  int n0 = ch*32;

  __shared__ float wTs[32*240];
  __shared__ float fis[32*16];
  __shared__ float v3s[240];
  __shared__ float accs[3840];

  for (int i=tid; i<1920; i+=256)
    ((float4*)wTs)[i] = ((const float4*)(wT + (size_t)n0*240))[i];
  for (int i=tid; i<128; i+=256)
    ((float4*)fis)[i] = ((const float4*)(v2 + ((size_t)b*NFC + n0)*16))[i];
  if (WITH_SM && tid < 240) v3s[tid] = v3[(size_t)b*240 + tid];
  __syncthreads();

  float acc[15];
  #pragma unroll
  for (int m=0;m<15;m++) acc[m]=0.f;

  #pragma unroll
  for (int i=0;i<2;i++){
    int nl = nloc*2 + i;
    float4 fv = *(const float4*)&fis[nl*16 + a*4];
    float votes[15], lg[15];
    #pragma unroll
    for (int m=0;m<15;m++){
      float4 wv = *(const float4*)&wTs[nl*240 + m*16 + d*4];
      float vt = fv.x*wv.x + fv.y*wv.y + fv.z*wv.z + fv.w*wv.w;
      votes[m] = vt;
      if (WITH_SM){
        float p = vt * v3s[m*16 + ad];
        p += __shfl_xor(p,1); p += __shfl_xor(p,2);
        p += __shfl_xor(p,4); p += __shfl_xor(p,8);
        lg[m] = p * 0.25f;
      }
    }
    if (WITH_SM){
      float mx = lg[0];
      #pragma unroll
      for (int m=1;m<15;m++) mx = fmaxf(mx, lg[m]);
      float se = 0.f;
      #pragma unroll
      for (int m=0;m<15;m++){ lg[m] = __expf(lg[m]-mx); se += lg[m]; }
      float inv = 1.f/se;
      float s2 = 0.f;
      #pragma unroll
      for (int m=0;m<15;m++){ lg[m] *= inv; s2 += lg[m]; }
      float inv2 = 1.f/(s2 + 1e-10f);
      #pragma unroll
      for (int m=0;m<15;m++) acc[m] += lg[m]*inv2*votes[m];
    } else {
      #pragma unroll
      for (int m=0;m<15;m++) acc[m] += votes[m]*(1.f/15.f);
    }
  }
  #pragma unroll
  for (int m=0;m<15;m++) accs[(m*16+ad)*16 + nloc] = acc[m];
  __syncthreads();
  if (tid < 240){
    float s = 0.f;
    #pragma unroll
    for (int k=0;k<16;k++) s += accs[tid*16 + k];
    part[((size_t)b*NCH + ch)*240 + tid] = s;
  }
}

// ---------------- kernel 9: reduce partials -> LN -> v3 ----------------
__global__ __launch_bounds__(240) void reduce_v3_kernel(
    const float* __restrict__ part, const float* __restrict__ g,
    const float* __restrict__ bt, float* __restrict__ v3)
{
  int b = blockIdx.x; int tid = threadIdx.x;
  int ad = tid & 15;
  float s = 0.f;
  for (int ch=0; ch<NCH; ++ch) s += part[((size_t)b*NCH + ch)*240 + tid];
  float tot = s;
  tot += __shfl_xor(tot,1); tot += __shfl_xor(tot,2);
  tot += __shfl_xor(tot,4); tot += __shfl_xor(tot,8);
  float mu = tot*(1.f/16.f);
  float df = s - mu;
  float q = df*df;
  q += __shfl_xor(q,1); q += __shfl_xor(q,2);
  q += __shfl_xor(q,4); q += __shfl_xor(q,8);
  float rs = rsqrtf(q*(1.f/16.f) + 1e-5f);
  v3[(size_t)b*240 + tid] = df*rs*g[ad] + bt[ad];
}

// ---------------- kernel 10: reduce partials -> LN -> norm head -> out ----------------
__global__ __launch_bounds__(240) void reduce_out_kernel(
    const float* __restrict__ part, const float* __restrict__ g,
    const float* __restrict__ bt, float* __restrict__ out)
{
  int b = blockIdx.x; int tid = threadIdx.x;
  int m = tid >> 4; int ad = tid & 15;
  float s = 0.f;
  for (int ch=0; ch<NCH; ++ch) s += part[((size_t)b*NCH + ch)*240 + tid];
  float tot = s;
  tot += __shfl_xor(tot,1); tot += __shfl_xor(tot,2);
  tot += __shfl_xor(tot,4); tot += __shfl_xor(tot,8);
  float mu = tot*(1.f/16.f);
  float df = s - mu;
  float q = df*df;
  q += __shfl_xor(q,1); q += __shfl_xor(q,2);
  q += __shfl_xor(q,4); q += __shfl_xor(q,8);
  float rs = rsqrtf(q*(1.f/16.f) + 1e-5f);
  float v = df*rs*g[ad] + bt[ad];
  float q2 = v*v;
  q2 += __shfl_xor(q2,1); q2 += __shfl_xor(q2,2);
  q2 += __shfl_xor(q2,4); q2 += __shfl_xor(q2,8);
  if (ad == 0) out[(size_t)b*15 + m] = q2/(1.f+q2);
}

// =================================================================================
extern "C" void kernel_launch(void* const* d_in, const int* in_sizes, int n_in,
                              void* d_out, int out_size, void* d_ws, size_t ws_size,
                              hipStream_t stream) {
  const float* code     = (const float*)d_in[0];
  const float* codebook = (const float*)d_in[1];
  const float* w_ih0    = (const float*)d_in[2];
  const float* w_hh0    = (const float*)d_in[3];
  const float* b_ih0    = (const float*)d_in[4];
  const float* b_hh0    = (const float*)d_in[5];
  const float* w_ih1    = (const float*)d_in[6];
  const float* w_hh1    = (const float*)d_in[7];
  const float* b_ih1    = (const float*)d_in[8];
  const float* b_hh1    = (const float*)d_in[9];
  const float* ln0g     = (const float*)d_in[10];
  const float* ln0b     = (const float*)d_in[11];
  const float* w1       = (const float*)d_in[12];
  const float* ln1g     = (const float*)d_in[13];
  const float* ln1b     = (const float*)d_in[14];
  const float* w2       = (const float*)d_in[15];
  const float* ln2g     = (const float*)d_in[16];
  const float* ln2b     = (const float*)d_in[17];
  const float* wfc      = (const float*)d_in[18];
  const float* lnfg     = (const float*)d_in[19];
  const float* lnfb     = (const float*)d_in[20];
  const int*   x        = (const int*)d_in[21];
  float* out = (float*)d_out;
  float* ws  = (float*)d_ws;

  float* gi   = ws + 0;
  __hip_bfloat16* v1t = (__hip_bfloat16*)(ws + 0);
  float* v2f  = ws + 4849664;
  float* wT   = ws + 9568256;
  float* part = ws + 10121216;
  __hip_bfloat16* h1b = (__hip_bfloat16*)(ws + 14745600);
  float* h2   = ws + 17203200;
  float* c_buf= ws + 17203200;
  __hip_bfloat16* in_t0 = (__hip_bfloat16*)(ws + 22118400);
  __hip_bfloat16* A0b = (__hip_bfloat16*)(ws + 22118400);
  __hip_bfloat16* W0b = (__hip_bfloat16*)(ws + 24576000);
  __hip_bfloat16* W1b = (__hip_bfloat16*)(ws + 24637440);
  float* v3   = ws + 24735744;
  __hip_bfloat16* Wc1b = (__hip_bfloat16*)(ws + 24766464);
  __hip_bfloat16* Wc2b = (__hip_bfloat16*)(ws + 24772608);

  softmax_c_kernel<<<(M_TOK*8 + 255)/256, 256, 0, stream>>>(code, x, c_buf);
  embed_bf16_kernel<<<(M_TOK*160 + 255)/256, 256, 0, stream>>>(c_buf, codebook, A0b, 160);
  convW_kernel<<<(768*160 + 255)/256, 256, 0, stream>>>(w_ih0, W0b, 768, 150, 160);
  convW_kernel<<<(768*256 + 255)/256, 256, 0, stream>>>(w_ih1, W1b, 768, 256, 256);
  convWc_kernel<<<(128*96 + 255)/256, 256, 0, stream>>>(w1, Wc1b, 8);
  convWc_kernel<<<(128*384 + 255)/256, 256, 0, stream>>>(w2, Wc2b, 32);
  gemm_mfma_kernel<<<dim3(6,150), 256, 0, stream>>>(A0b, W0b, b_ih0, gi, 160);
  gru_scan_kernel<__hip_bfloat16><<<256, 768, 0, stream>>>(gi, w_hh0, b_hh0, h1b, 256, (size_t)128);
  gemm_mfma_kernel<<<dim3(6,150), 256, 0, stream>>>(h1b, W1b, b_ih1, gi, 256);
  gru_scan_kernel<float><<<256, 768, 0, stream>>>(gi, w_hh1, b_hh1, h2, 128, (size_t)M_TOK*HIDN);
  ln0_kernel<<<(B_SZ*8*L_SZ + 255)/256, 256, 0, stream>>>(h2, ln0g, ln0b, in_t0);
  caps_mfma_kernel<1><<<296, 256, 0, stream>>>(in_t0, Wc1b, ln1g, ln1b, (void*)v1t);
  caps_mfma_kernel<2><<<288, 256, 0, stream>>>(v1t, Wc2b, ln2g, ln2b, (void*)v2f);
  transposeW_kernel<<<(NFC*240 + 255)/256, 256, 0, stream>>>(wfc, wT);
  route_pass_kernel<0><<<dim3(NCH,B_SZ), 256, 0, stream>>>(v2f, wT, nullptr, part);
  reduce_v3_kernel<<<B_SZ, 240, 0, stream>>>(part, lnfg, lnfb, v3);
  route_pass_kernel<1><<<dim3(NCH,B_SZ), 256, 0, stream>>>(v2f, wT, v3, part);
  reduce_out_kernel<<<B_SZ, 240, 0, stream>>>(part, lnfg, lnfb, out);
}

// Round 7
// 538.485 us; speedup vs baseline: 10.0397x; 1.0830x over previous
//
#include <hip/hip_runtime.h>
#include <hip/hip_bf16.h>
#include <cstdint>

// Model constants
#define B_SZ 128
#define L_SZ 150
#define E_SZ 150
#define HIDN 128
#define M_TOK (B_SZ*L_SZ)   // 19200
#define G3 384              // 3*HID gates
#define NFC 2304            // capsule-FC input count
#define NCH 72              // n-chunks per b (32 n each)

typedef __attribute__((ext_vector_type(8))) short bf16x8;
typedef __attribute__((ext_vector_type(4))) float f32x4;

__device__ __forceinline__ float sigm(float x){ return 1.f/(1.f+__expf(-x)); }

__device__ __forceinline__ void storeval(float* p, float v){ *p = v; }
__device__ __forceinline__ void storeval(__hip_bfloat16* p, float v){ *p = __float2bfloat16(v); }

// ---------------- kernel 1: c[t][32] = softmax over last-4 of code[x[t]] ----------------
__global__ void softmax_c_kernel(const float* __restrict__ code, const int* __restrict__ x,
                                 float* __restrict__ c){
  int idx = blockIdx.x*blockDim.x + threadIdx.x;
  if (idx >= M_TOK*8) return;
  int t = idx >> 3, j = idx & 7;
  int tok = x[t];
  const float* p = code + ((size_t)tok*32 + j*4);
  float a0=p[0],a1=p[1],a2=p[2],a3=p[3];
  float mx = fmaxf(fmaxf(a0,a1),fmaxf(a2,a3));
  float e0=__expf(a0-mx),e1=__expf(a1-mx),e2=__expf(a2-mx),e3=__expf(a3-mx);
  float inv = 1.f/(e0+e1+e2+e3);
  float* q = c + ((size_t)t*32 + j*4);
  q[0]=e0*inv; q[1]=e1*inv; q[2]=e2*inv; q[3]=e3*inv;
}

// ---------------- kernel 2: emb bf16 padded ----------------
__global__ void embed_bf16_kernel(const float* __restrict__ c, const float* __restrict__ cb,
                                  __hip_bfloat16* __restrict__ A0, int Kp){
  int idx = blockIdx.x*blockDim.x + threadIdx.x;
  if (idx >= M_TOK*160) return;
  int t = idx / 160; int e = idx - t*160;
  float acc = 0.f;
  if (e < E_SZ){
    const float* cr = c + (size_t)t*32;
    #pragma unroll
    for (int i=0;i<32;i++) acc += cr[i]*cb[i*E_SZ + e];
  }
  A0[(size_t)t*Kp + e] = __float2bfloat16(acc);
}

// ---------------- weight fp32->bf16 (K-padded) ----------------
__global__ void convW_kernel(const float* __restrict__ src, __hip_bfloat16* __restrict__ dst,
                             int N, int K, int Kp){
  int idx = blockIdx.x*blockDim.x + threadIdx.x;
  if (idx >= N*Kp) return;
  int n = idx / Kp; int k = idx - n*Kp;
  float v = (k < K) ? src[(size_t)n*K + k] : 0.f;
  dst[idx] = __float2bfloat16(v);
}

// ---------------- capsule-conv weight prep: dst[j=(m*4+d)][k*NCAPS*4 + n*4 + x] ----------------
__global__ void convWc_kernel(const float* __restrict__ w, __hip_bfloat16* __restrict__ dst,
                              int NCAPS){
  int KP = 12*NCAPS;
  int idx = blockIdx.x*blockDim.x + threadIdx.x;
  if (idx >= 128*KP) return;
  int j = idx / KP; int rem = idx - j*KP;
  int k = rem/(4*NCAPS); int r2 = rem - k*4*NCAPS; int n = r2>>2; int xx = r2&3;
  int m = j>>2, d = j&3;
  dst[idx] = __float2bfloat16(w[(size_t)(((k*NCAPS+n)*4+xx)*4+d)*32 + m]);
}

// ---------------- kernel 3: MFMA GEMM (input projections) ----------------
__global__ __launch_bounds__(256) void gemm_mfma_kernel(
    const __hip_bfloat16* __restrict__ A, const __hip_bfloat16* __restrict__ W,
    const float* __restrict__ bias, float* __restrict__ out, int Kp)
{
  __shared__ __hip_bfloat16 As[128*32];
  __shared__ __hip_bfloat16 Bs[128*32];
  int tid = threadIdx.x;
  int m0 = blockIdx.y*128, n0 = blockIdx.x*128;
  int lane = tid & 63, wid = tid >> 6;
  int wr = wid >> 1, wc = wid & 1;
  int srow = tid >> 2, scol = (tid & 3) * 8;

  f32x4 acc[4][4];
  #pragma unroll
  for (int i=0;i<4;i++)
    #pragma unroll
    for (int j=0;j<4;j++) acc[i][j] = (f32x4){0.f,0.f,0.f,0.f};

  int r = lane & 15, kq = (lane >> 4) * 8;

  for (int k0 = 0; k0 < Kp; k0 += 32){
    __builtin_amdgcn_global_load_lds(
      (const __attribute__((address_space(1))) void*)(A + (size_t)(m0+srow)*Kp + k0 + scol),
      (__attribute__((address_space(3))) void*)(As + tid*8), 16, 0, 0);
    __builtin_amdgcn_global_load_lds(
      (const __attribute__((address_space(1))) void*)(A + (size_t)(m0+64+srow)*Kp + k0 + scol),
      (__attribute__((address_space(3))) void*)(As + 2048 + tid*8), 16, 0, 0);
    __builtin_amdgcn_global_load_lds(
      (const __attribute__((address_space(1))) void*)(W + (size_t)(n0+srow)*Kp + k0 + scol),
      (__attribute__((address_space(3))) void*)(Bs + tid*8), 16, 0, 0);
    __builtin_amdgcn_global_load_lds(
      (const __attribute__((address_space(1))) void*)(W + (size_t)(n0+64+srow)*Kp + k0 + scol),
      (__attribute__((address_space(3))) void*)(Bs + 2048 + tid*8), 16, 0, 0);
    __syncthreads();

    bf16x8 aF[4], bF[4];
    #pragma unroll
    for (int mi=0;mi<4;mi++) aF[mi] = *(const bf16x8*)(As + (wr*64 + mi*16 + r)*32 + kq);
    #pragma unroll
    for (int nj=0;nj<4;nj++) bF[nj] = *(const bf16x8*)(Bs + (wc*64 + nj*16 + r)*32 + kq);
    #pragma unroll
    for (int mi=0;mi<4;mi++)
      #pragma unroll
      for (int nj=0;nj<4;nj++)
        acc[mi][nj] = __builtin_amdgcn_mfma_f32_16x16x32_bf16(aF[mi], bF[nj], acc[mi][nj], 0, 0, 0);
    __syncthreads();
  }

  #pragma unroll
  for (int nj=0;nj<4;nj++){
    int n = n0 + wc*64 + nj*16 + (lane & 15);
    int dir = (n >= G3) ? 1 : 0; int g = n - dir*G3;
    float bv = bias[n];
    #pragma unroll
    for (int mi=0;mi<4;mi++){
      #pragma unroll
      for (int r2=0;r2<4;r2++){
        int m = m0 + wr*64 + mi*16 + (lane>>4)*4 + r2;
        out[((size_t)dir*M_TOK + m)*G3 + g] = acc[mi][nj][r2] + bv;
      }
    }
  }
}

// ---------------- kernel 4: GRU scan (768 threads = 12 waves = 1 block/CU) ----------------
// R7: asm-pin the weight registers. launch_bounds(768,3) alone did NOT stop the
// allocator from rematerializing w[16] as per-step global loads (R6: VGPR=52 < 64).
// An asm volatile OUTPUT cannot be re-executed, so the 64 weight VGPRs must stay live.
template <typename OT>
__global__ __launch_bounds__(768, 3) void gru_scan_kernel(
    const float* __restrict__ gi, const float* __restrict__ whh,
    const float* __restrict__ bhh, OT* __restrict__ out, int rowStride, size_t dirOffset)
{
  int bx = blockIdx.x; int dir = bx>>7; int b = bx&127;
  int tid = threadIdx.x;
  int half = (tid >= 384) ? 1 : 0;
  int row = tid - half*384;
  __shared__ float s_h[128];
  __shared__ float s_part[2][384];
  float4 w[16];
  const float4* wrow = (const float4*)(whh + (size_t)(dir*G3 + row)*HIDN + half*64);
  #pragma unroll
  for (int i=0;i<16;i++) w[i] = wrow[i];
  // pin weights in VGPRs: un-rematerializable defs
  #pragma unroll
  for (int i=0;i<16;i++)
    asm volatile("" : "+v"(w[i].x), "+v"(w[i].y), "+v"(w[i].z), "+v"(w[i].w));
  float bias = (half==0) ? bhh[dir*G3 + row] : 0.f;
  if (tid < 128) s_h[tid] = 0.f;
  const float* gib = gi + ((size_t)dir*M_TOK + (size_t)b*L_SZ)*G3;
  float ir=0.f, iz=0.f, inn=0.f;
  {
    int t0 = dir ? (L_SZ-1) : 0;
    if (tid < 128){
      const float* gr = gib + (size_t)t0*G3;
      ir = gr[tid]; iz = gr[128+tid]; inn = gr[256+tid];
    }
  }
  __syncthreads();
  for (int s=0; s<L_SZ; ++s){
    int t = dir ? (L_SZ-1 - s) : s;
    const float4* h4 = ((const float4*)s_h) + half*16;
    float p0=bias, p1=0.f;
    #pragma unroll
    for (int i=0;i<16;i+=2){
      float4 ha=h4[i], hb=h4[i+1];
      p0 += w[i].x*ha.x + w[i].y*ha.y + w[i].z*ha.z + w[i].w*ha.w;
      p1 += w[i+1].x*hb.x + w[i+1].y*hb.y + w[i+1].z*hb.z + w[i+1].w*hb.w;
    }
    s_part[half][row] = p0+p1;
    float nir=0.f, niz=0.f, ninn=0.f;
    if (tid < 128 && s+1 < L_SZ){
      int tn = dir ? (t-1) : (t+1);
      const float* gr = gib + (size_t)tn*G3;
      nir = gr[tid]; niz = gr[128+tid]; ninn = gr[256+tid];
    }
    __syncthreads();
    if (tid < 128){
      float hr = s_part[0][tid]     + s_part[1][tid];
      float hz = s_part[0][128+tid] + s_part[1][128+tid];
      float hn = s_part[0][256+tid] + s_part[1][256+tid];
      float rr = sigm(ir+hr);
      float zz = sigm(iz+hz);
      float xn = inn + rr*hn;
      float e2 = __expf(2.f*xn);
      float nn = 1.f - 2.f/(e2+1.f);
      float hnew = (1.f-zz)*nn + zz*s_h[tid];
      s_h[tid] = hnew;
      storeval(&out[(size_t)(b*L_SZ + t)*rowStride + (size_t)dir*dirOffset + tid], hnew);
    }
    __syncthreads();
    ir=nir; iz=niz; inn=ninn;
  }
}

// ---------------- kernel 5: ln0 -> in_t0[b][t][a][n][x] bf16 ----------------
__global__ void ln0_kernel(const float* __restrict__ h2, const float* __restrict__ g,
                           const float* __restrict__ bt, __hip_bfloat16* __restrict__ in_t0){
  int idx = blockIdx.x*blockDim.x + threadIdx.x;
  if (idx >= B_SZ*8*L_SZ) return;
  int t = idx % L_SZ; int bn = idx / L_SZ; int n = bn & 7; int b = bn >> 3;
  const float* f0 = h2 + (size_t)(b*L_SZ+t)*HIDN + n*16;
  const float* f1 = f0 + (size_t)M_TOK*HIDN;
  float v[16]; float s = 0.f;
  #pragma unroll
  for (int d=0;d<16;d++){ v[d] = f0[d] + f1[d]; s += v[d]; }
  float mu = s*(1.f/16.f);
  float q = 0.f;
  #pragma unroll
  for (int d=0;d<16;d++){ float df = v[d]-mu; q += df*df; }
  float rs = rsqrtf(q*(1.f/16.f) + 1e-5f);
  __hip_bfloat16* o = in_t0 + (size_t)b*19200 + t*128 + n*4;
  #pragma unroll
  for (int dd=0;dd<16;dd++){
    int a = dd>>2, xx = dd&3;
    o[a*32 + xx] = __float2bfloat16((v[dd]-mu)*rs*g[dd] + bt[dd]);
  }
}

// ---------------- kernel 6: capsule conv as MFMA GEMM with fused LN epilogue ----------------
template<int CONV>
__global__ __launch_bounds__(256) void caps_mfma_kernel(
    const __hip_bfloat16* __restrict__ A, const __hip_bfloat16* __restrict__ W,
    const float* __restrict__ gam, const float* __restrict__ bet,
    void* __restrict__ outv)
{
  constexpr int KP   = (CONV==1) ? 96 : 384;
  constexpr int KTAP = (CONV==1) ? 32 : 128;
  constexpr int S    = (CONV==1) ? 2 : 1;
  constexpr int H    = (CONV==1) ? 74 : 72;
  constexpr int RSTR = (CONV==1) ? 128 : 512;
  constexpr int BSTR = (CONV==1) ? 19200 : 37888;
  __shared__ __hip_bfloat16 As[128*32];
  __shared__ __hip_bfloat16 Bs[128*32];
  int tid = threadIdx.x;
  int m0 = blockIdx.x*128;
  int lane = tid&63, wid = tid>>6;
  int wr = wid>>1, wc = wid&1;
  int srow = tid>>2, scol = (tid&3)*8;

  int row1 = m0 + srow, row2 = row1 + 64;
  int bh1 = row1>>2, a1 = row1&3; int b1 = bh1/H, h1 = bh1 - b1*H;
  int bh2 = row2>>2, a2 = row2&3; int b2 = bh2/H, h2_ = bh2 - b2*H;
  const __hip_bfloat16* arow1 = A + (size_t)b1*BSTR + (size_t)(h1*S)*RSTR + a1*KTAP;
  const __hip_bfloat16* arow2 = A + (size_t)b2*BSTR + (size_t)(h2_*S)*RSTR + a2*KTAP;

  f32x4 acc[4][4];
  #pragma unroll
  for (int i=0;i<4;i++)
    #pragma unroll
    for (int j=0;j<4;j++) acc[i][j] = (f32x4){0.f,0.f,0.f,0.f};

  int r = lane&15, kq = (lane>>4)*8;

  for (int k0=0; k0<KP; k0+=32){
    int tap = k0/KTAP;
    int off = k0 - tap*KTAP + scol;
    __builtin_amdgcn_global_load_lds(
      (const __attribute__((address_space(1))) void*)(arow1 + tap*RSTR + off),
      (__attribute__((address_space(3))) void*)(As + tid*8), 16, 0, 0);
    __builtin_amdgcn_global_load_lds(
      (const __attribute__((address_space(1))) void*)(arow2 + tap*RSTR + off),
      (__attribute__((address_space(3))) void*)(As + 2048 + tid*8), 16, 0, 0);
    __builtin_amdgcn_global_load_lds(
      (const __attribute__((address_space(1))) void*)(W + (size_t)srow*KP + k0 + scol),
      (__attribute__((address_space(3))) void*)(Bs + tid*8), 16, 0, 0);
    __builtin_amdgcn_global_load_lds(
      (const __attribute__((address_space(1))) void*)(W + (size_t)(64+srow)*KP + k0 + scol),
      (__attribute__((address_space(3))) void*)(Bs + 2048 + tid*8), 16, 0, 0);
    __syncthreads();

    bf16x8 aF[4], bF[4];
    #pragma unroll
    for (int mi=0;mi<4;mi++) aF[mi] = *(const bf16x8*)(As + (wr*64 + mi*16 + r)*32 + kq);
    #pragma unroll
    for (int nj=0;nj<4;nj++) bF[nj] = *(const bf16x8*)(Bs + (wc*64 + nj*16 + r)*32 + kq);
    #pragma unroll
    for (int mi=0;mi<4;mi++)
      #pragma unroll
      for (int nj=0;nj<4;nj++)
        acc[mi][nj] = __builtin_amdgcn_mfma_f32_16x16x32_bf16(aF[mi], bF[nj], acc[mi][nj], 0, 0, 0);
    __syncthreads();
  }

  #pragma unroll
  for (int mi=0;mi<4;mi++)
    #pragma unroll
    for (int nj=0;nj<4;nj++){
      int jj = wc*64 + nj*16 + (lane&15);
      int rowb = m0 + wr*64 + mi*16 + (lane>>4)*4;
      float vv[4];
      #pragma unroll
      for (int r2=0;r2<4;r2++) vv[r2] = acc[mi][nj][r2]*(1.f/32.f);
      float s = vv[0]+vv[1]+vv[2]+vv[3];
      s += __shfl_xor(s,1); s += __shfl_xor(s,2);
      float mu = s*(1.f/16.f);
      float q = 0.f;
      #pragma unroll
      for (int r2=0;r2<4;r2++){ float df = vv[r2]-mu; q += df*df; }
      q += __shfl_xor(q,1); q += __shfl_xor(q,2);
      float rs = rsqrtf(q*(1.f/16.f) + 1e-5f);
      int d = jj&3;
      #pragma unroll
      for (int r2=0;r2<4;r2++){
        float o = (vv[r2]-mu)*rs*gam[r2*4+d] + bet[r2*4+d];
        if constexpr (CONV==1){
          ((__hip_bfloat16*)outv)[(size_t)(rowb+r2)*128 + jj] = __float2bfloat16(o);
        } else {
          int rw = rowb + r2; int bh = rw>>2, a = rw&3; int bb = bh/H, hh = bh - bb*H;
          ((float*)outv)[((size_t)bb*NFC + (jj>>2)*H + hh)*16 + a*4 + d] = o;
        }
      }
    }
}

// ---------------- kernel 7: transpose wfc -> wT[n][m][d][x] ----------------
__global__ void transposeW_kernel(const float* __restrict__ wfc, float* __restrict__ wT){
  int idx = blockIdx.x*blockDim.x + threadIdx.x;
  if (idx >= NFC*240) return;
  int n = idx / 240; int r = idx - n*240;
  int m = r >> 4; int dd = (r >> 2) & 3; int xx = r & 3;
  wT[idx] = wfc[(size_t)((n*4+xx)*4+dd)*15 + m];
}

// ---------------- kernel 8: routing pass ----------------
template<int WITH_SM>
__global__ __launch_bounds__(256) void route_pass_kernel(
    const float* __restrict__ v2, const float* __restrict__ wT,
    const float* __restrict__ v3, float* __restrict__ part)
{
  int ch = blockIdx.x, b = blockIdx.y;
  int tid = threadIdx.x;
  int nloc = tid >> 4;
  int ad = tid & 15; int a = ad >> 2; int d = ad & 3;
  int n0 = ch*32;

  __shared__ float wTs[32*240];
  __shared__ float fis[32*16];
  __shared__ float v3s[240];
  __shared__ float accs[3840];

  for (int i=tid; i<1920; i+=256)
    ((float4*)wTs)[i] = ((const float4*)(wT + (size_t)n0*240))[i];
  for (int i=tid; i<128; i+=256)
    ((float4*)fis)[i] = ((const float4*)(v2 + ((size_t)b*NFC + n0)*16))[i];
  if (WITH_SM && tid < 240) v3s[tid] = v3[(size_t)b*240 + tid];
  __syncthreads();

  float acc[15];
  #pragma unroll
  for (int m=0;m<15;m++) acc[m]=0.f;

  #pragma unroll
  for (int i=0;i<2;i++){
    int nl = nloc*2 + i;
    float4 fv = *(const float4*)&fis[nl*16 + a*4];
    float votes[15], lg[15];
    #pragma unroll
    for (int m=0;m<15;m++){
      float4 wv = *(const float4*)&wTs[nl*240 + m*16 + d*4];
      float vt = fv.x*wv.x + fv.y*wv.y + fv.z*wv.z + fv.w*wv.w;
      votes[m] = vt;
      if (WITH_SM){
        float p = vt * v3s[m*16 + ad];
        p += __shfl_xor(p,1); p += __shfl_xor(p,2);
        p += __shfl_xor(p,4); p += __shfl_xor(p,8);
        lg[m] = p * 0.25f;
      }
    }
    if (WITH_SM){
      float mx = lg[0];
      #pragma unroll
      for (int m=1;m<15;m++) mx = fmaxf(mx, lg[m]);
      float se = 0.f;
      #pragma unroll
      for (int m=0;m<15;m++){ lg[m] = __expf(lg[m]-mx); se += lg[m]; }
      float inv = 1.f/se;
      float s2 = 0.f;
      #pragma unroll
      for (int m=0;m<15;m++){ lg[m] *= inv; s2 += lg[m]; }
      float inv2 = 1.f/(s2 + 1e-10f);
      #pragma unroll
      for (int m=0;m<15;m++) acc[m] += lg[m]*inv2*votes[m];
    } else {
      #pragma unroll
      for (int m=0;m<15;m++) acc[m] += votes[m]*(1.f/15.f);
    }
  }
  #pragma unroll
  for (int m=0;m<15;m++) accs[(m*16+ad)*16 + nloc] = acc[m];
  __syncthreads();
  if (tid < 240){
    float s = 0.f;
    #pragma unroll
    for (int k=0;k<16;k++) s += accs[tid*16 + k];
    part[((size_t)b*NCH + ch)*240 + tid] = s;
  }
}

// ---------------- kernel 9: reduce partials -> LN -> v3 ----------------
__global__ __launch_bounds__(240) void reduce_v3_kernel(
    const float* __restrict__ part, const float* __restrict__ g,
    const float* __restrict__ bt, float* __restrict__ v3)
{
  int b = blockIdx.x; int tid = threadIdx.x;
  int ad = tid & 15;
  float s = 0.f;
  for (int ch=0; ch<NCH; ++ch) s += part[((size_t)b*NCH + ch)*240 + tid];
  float tot = s;
  tot += __shfl_xor(tot,1); tot += __shfl_xor(tot,2);
  tot += __shfl_xor(tot,4); tot += __shfl_xor(tot,8);
  float mu = tot*(1.f/16.f);
  float df = s - mu;
  float q = df*df;
  q += __shfl_xor(q,1); q += __shfl_xor(q,2);
  q += __shfl_xor(q,4); q += __shfl_xor(q,8);
  float rs = rsqrtf(q*(1.f/16.f) + 1e-5f);
  v3[(size_t)b*240 + tid] = df*rs*g[ad] + bt[ad];
}

// ---------------- kernel 10: reduce partials -> LN -> norm head -> out ----------------
__global__ __launch_bounds__(240) void reduce_out_kernel(
    const float* __restrict__ part, const float* __restrict__ g,
    const float* __restrict__ bt, float* __restrict__ out)
{
  int b = blockIdx.x; int tid = threadIdx.x;
  int m = tid >> 4; int ad = tid & 15;
  float s = 0.f;
  for (int ch=0; ch<NCH; ++ch) s += part[((size_t)b*NCH + ch)*240 + tid];
  float tot = s;
  tot += __shfl_xor(tot,1); tot += __shfl_xor(tot,2);
  tot += __shfl_xor(tot,4); tot += __shfl_xor(tot,8);
  float mu = tot*(1.f/16.f);
  float df = s - mu;
  float q = df*df;
  q += __shfl_xor(q,1); q += __shfl_xor(q,2);
  q += __shfl_xor(q,4); q += __shfl_xor(q,8);
  float rs = rsqrtf(q*(1.f/16.f) + 1e-5f);
  float v = df*rs*g[ad] + bt[ad];
  float q2 = v*v;
  q2 += __shfl_xor(q2,1); q2 += __shfl_xor(q2,2);
  q2 += __shfl_xor(q2,4); q2 += __shfl_xor(q2,8);
  if (ad == 0) out[(size_t)b*15 + m] = q2/(1.f+q2);
}

// =================================================================================
extern "C" void kernel_launch(void* const* d_in, const int* in_sizes, int n_in,
                              void* d_out, int out_size, void* d_ws, size_t ws_size,
                              hipStream_t stream) {
  const float* code     = (const float*)d_in[0];
  const float* codebook = (const float*)d_in[1];
  const float* w_ih0    = (const float*)d_in[2];
  const float* w_hh0    = (const float*)d_in[3];
  const float* b_ih0    = (const float*)d_in[4];
  const float* b_hh0    = (const float*)d_in[5];
  const float* w_ih1    = (const float*)d_in[6];
  const float* w_hh1    = (const float*)d_in[7];
  const float* b_ih1    = (const float*)d_in[8];
  const float* b_hh1    = (const float*)d_in[9];
  const float* ln0g     = (const float*)d_in[10];
  const float* ln0b     = (const float*)d_in[11];
  const float* w1       = (const float*)d_in[12];
  const float* ln1g     = (const float*)d_in[13];
  const float* ln1b     = (const float*)d_in[14];
  const float* w2       = (const float*)d_in[15];
  const float* ln2g     = (const float*)d_in[16];
  const float* ln2b     = (const float*)d_in[17];
  const float* wfc      = (const float*)d_in[18];
  const float* lnfg     = (const float*)d_in[19];
  const float* lnfb     = (const float*)d_in[20];
  const int*   x        = (const int*)d_in[21];
  float* out = (float*)d_out;
  float* ws  = (float*)d_ws;

  float* gi   = ws + 0;
  __hip_bfloat16* v1t = (__hip_bfloat16*)(ws + 0);
  float* v2f  = ws + 4849664;
  float* wT   = ws + 9568256;
  float* part = ws + 10121216;
  __hip_bfloat16* h1b = (__hip_bfloat16*)(ws + 14745600);
  float* h2   = ws + 17203200;
  float* c_buf= ws + 17203200;
  __hip_bfloat16* in_t0 = (__hip_bfloat16*)(ws + 22118400);
  __hip_bfloat16* A0b = (__hip_bfloat16*)(ws + 22118400);
  __hip_bfloat16* W0b = (__hip_bfloat16*)(ws + 24576000);
  __hip_bfloat16* W1b = (__hip_bfloat16*)(ws + 24637440);
  float* v3   = ws + 24735744;
  __hip_bfloat16* Wc1b = (__hip_bfloat16*)(ws + 24766464);
  __hip_bfloat16* Wc2b = (__hip_bfloat16*)(ws + 24772608);

  softmax_c_kernel<<<(M_TOK*8 + 255)/256, 256, 0, stream>>>(code, x, c_buf);
  embed_bf16_kernel<<<(M_TOK*160 + 255)/256, 256, 0, stream>>>(c_buf, codebook, A0b, 160);
  convW_kernel<<<(768*160 + 255)/256, 256, 0, stream>>>(w_ih0, W0b, 768, 150, 160);
  convW_kernel<<<(768*256 + 255)/256, 256, 0, stream>>>(w_ih1, W1b, 768, 256, 256);
  convWc_kernel<<<(128*96 + 255)/256, 256, 0, stream>>>(w1, Wc1b, 8);
  convWc_kernel<<<(128*384 + 255)/256, 256, 0, stream>>>(w2, Wc2b, 32);
  gemm_mfma_kernel<<<dim3(6,150), 256, 0, stream>>>(A0b, W0b, b_ih0, gi, 160);
  gru_scan_kernel<__hip_bfloat16><<<256, 768, 0, stream>>>(gi, w_hh0, b_hh0, h1b, 256, (size_t)128);
  gemm_mfma_kernel<<<dim3(6,150), 256, 0, stream>>>(h1b, W1b, b_ih1, gi, 256);
  gru_scan_kernel<float><<<256, 768, 0, stream>>>(gi, w_hh1, b_hh1, h2, 128, (size_t)M_TOK*HIDN);
  ln0_kernel<<<(B_SZ*8*L_SZ + 255)/256, 256, 0, stream>>>(h2, ln0g, ln0b, in_t0);
  caps_mfma_kernel<1><<<296, 256, 0, stream>>>(in_t0, Wc1b, ln1g, ln1b, (void*)v1t);
  caps_mfma_kernel<2><<<288, 256, 0, stream>>>(v1t, Wc2b, ln2g, ln2b, (void*)v2f);
  transposeW_kernel<<<(NFC*240 + 255)/256, 256, 0, stream>>>(wfc, wT);
  route_pass_kernel<0><<<dim3(NCH,B_SZ), 256, 0, stream>>>(v2f, wT, nullptr, part);
  reduce_v3_kernel<<<B_SZ, 240, 0, stream>>>(part, lnfg, lnfb, v3);
  route_pass_kernel<1><<<dim3(NCH,B_SZ), 256, 0, stream>>>(v2f, wT, v3, part);
  reduce_out_kernel<<<B_SZ, 240, 0, stream>>>(part, lnfg, lnfb, out);
}